// Round 5
// baseline (34718.829 us; speedup 1.0000x reference)
//
#include <hip/hip_runtime.h>
#include <math.h>

// BiLSTM-CRF, fp32. V=50000 B=64 T=256 D=256 H=256 C=32
//
// R4: weight-stationary LSTM; h exchanged ONLY through L2 (hx) with per-wave
// flag gating and wave-uniform broadcast loads. One __syncthreads per step;
// red[] double-buffered by parity. No hs/loader phase at all.
//
// ws layout (floats):
//   xg    : [2][64][256][1024]          33554432
//   hcat  : [64][256][512]               8388608
//   em    : [64][256][32]                 524288
//   hx    : [2buf][64grp][2seq][256]       65536
//   flags : [64grp][4mem][16pad] uint       4096  (dwords 0,1 = seq0,seq1)
//
// d_out: float32[16448] = paths[64][256] (as float) then best_score[64]

typedef unsigned long long ull;

// ---------------------------------------------------------------- K0z: zero flags
__global__ void k0z_zero(unsigned int* __restrict__ flags)
{
    int i = blockIdx.x * 1024 + threadIdx.x;
    if (i < 4096) flags[i] = 0u;
}

// ---------------------------------------------------------------- K1: embed + input GEMM
__global__ __launch_bounds__(256) void k1_xgemm(
    const int* __restrict__ sent, const int* __restrict__ lens,
    const float* __restrict__ emb,
    const float* __restrict__ wih_f, const float* __restrict__ wih_b,
    const float* __restrict__ bih_f, const float* __restrict__ bhh_f,
    const float* __restrict__ bih_b, const float* __restrict__ bhh_b,
    float* __restrict__ xg)
{
    const int bid = blockIdx.x;          // 2048 = 2 dir * 128 mt * 8 nt
    const int dir = bid >> 10;
    const int rem = bid & 1023;
    const int mt = rem >> 3, nt = rem & 7;
    const int r0 = mt * 128, j0 = nt * 128;
    const int b = r0 >> 8, t0 = r0 & 255;
    const float* __restrict__ wih = dir ? wih_b : wih_f;
    const float* __restrict__ bih = dir ? bih_b : bih_f;
    const float* __restrict__ bhh = dir ? bhh_b : bhh_f;

    __shared__ __align__(16) float At[32][132];
    __shared__ __align__(16) float Bt[32][132];
    __shared__ int tok_s[128];

    const int tid = threadIdx.x;
    if (tid < 128) {
        int t = t0 + tid;
        int tt = t;
        if (dir) { int L = lens[b]; if (t < L) tt = L - 1 - t; }
        tok_s[tid] = sent[b * 256 + tt];
    }
    __syncthreads();

    float acc[8][8];
    #pragma unroll
    for (int i = 0; i < 8; ++i)
        #pragma unroll
        for (int j = 0; j < 8; ++j) acc[i][j] = 0.f;

    const int lrow = tid >> 3;
    const int l8 = tid & 7;
    const int tx = tid & 15, ty = tid >> 4;

    for (int kc = 0; kc < 256; kc += 32) {
        #pragma unroll
        for (int it = 0; it < 4; ++it) {
            int row = lrow + it * 32;
            float4 va = *(const float4*)(emb + (size_t)tok_s[row] * 256 + kc + l8 * 4);
            At[l8*4+0][row] = va.x; At[l8*4+1][row] = va.y;
            At[l8*4+2][row] = va.z; At[l8*4+3][row] = va.w;
            float4 vb = *(const float4*)(wih + (size_t)(j0 + row) * 256 + kc + l8 * 4);
            Bt[l8*4+0][row] = vb.x; Bt[l8*4+1][row] = vb.y;
            Bt[l8*4+2][row] = vb.z; Bt[l8*4+3][row] = vb.w;
        }
        __syncthreads();
        #pragma unroll
        for (int k = 0; k < 32; ++k) {
            float4 a0 = *(const float4*)&At[k][ty*8];
            float4 a1 = *(const float4*)&At[k][ty*8+4];
            float4 b0 = *(const float4*)&Bt[k][tx*8];
            float4 b1 = *(const float4*)&Bt[k][tx*8+4];
            float av[8] = {a0.x,a0.y,a0.z,a0.w,a1.x,a1.y,a1.z,a1.w};
            float bv[8] = {b0.x,b0.y,b0.z,b0.w,b1.x,b1.y,b1.z,b1.w};
            #pragma unroll
            for (int i = 0; i < 8; ++i)
                #pragma unroll
                for (int j = 0; j < 8; ++j)
                    acc[i][j] += av[i] * bv[j];
        }
        __syncthreads();
    }

    float bias[8];
    {
        float4 p0 = *(const float4*)(bih + j0 + tx*8);
        float4 p1 = *(const float4*)(bih + j0 + tx*8 + 4);
        float4 q0 = *(const float4*)(bhh + j0 + tx*8);
        float4 q1 = *(const float4*)(bhh + j0 + tx*8 + 4);
        bias[0]=p0.x+q0.x; bias[1]=p0.y+q0.y; bias[2]=p0.z+q0.z; bias[3]=p0.w+q0.w;
        bias[4]=p1.x+q1.x; bias[5]=p1.y+q1.y; bias[6]=p1.z+q1.z; bias[7]=p1.w+q1.w;
    }
    #pragma unroll
    for (int i = 0; i < 8; ++i) {
        int r = r0 + ty*8 + i;
        int t = r & 255;
        float* orow = xg + ((size_t)(dir*64 + b) * 256 + t) * 1024 + j0 + tx*8;
        float4 o0, o1;
        o0.x = acc[i][0]+bias[0]; o0.y = acc[i][1]+bias[1];
        o0.z = acc[i][2]+bias[2]; o0.w = acc[i][3]+bias[3];
        o1.x = acc[i][4]+bias[4]; o1.y = acc[i][5]+bias[5];
        o1.z = acc[i][6]+bias[6]; o1.w = acc[i][7]+bias[7];
        *(float4*)orow = o0;
        *(float4*)(orow + 4) = o1;
    }
}

// ---------------------------------------------------------------- K2: weight-stationary LSTM
// 256 WGs: member m = blockIdx>>6 (64-unit slice), group g = blockIdx&63.
// Wave kg (tid>>7) covers k-units [32kg,32kg+32) -> source member src=kg>>1.
// Per step: A(poll src flag, broadcast-load h from L2, 128 FMA, red write)
//           -> 1 barrier -> BC(reduce + cell + hx store + release flag + hcat).
__global__ __launch_bounds__(1024)
__attribute__((amdgpu_waves_per_eu(4, 4)))
void k2_lstm(
    const float* __restrict__ whh_f, const float* __restrict__ whh_b,
    const float* __restrict__ xg, float* __restrict__ hcat,
    float* __restrict__ hx, unsigned int* __restrict__ flags)
{
    const int m = blockIdx.x >> 6;       // slice / member 0..3
    const int g = blockIdx.x & 63;       // group
    const int dir = g >> 5;
    const int b0 = (g & 31) * 2;
    const float* __restrict__ w = dir ? whh_b : whh_f;

    const int tid = threadIdx.x;
    const int kg = tid >> 7;             // 0..7 wave-pair-uniform
    const int rp = tid & 127;
    const int r0 = rp * 2;               // local rows {r0, r0+1}; r = gate*64+u
    const int gate = r0 >> 6;
    const int u0 = r0 & 63;
    const int kbase = kg * 32;
    const int src = kg >> 1;             // member owning this k-slice

    // ---- weights to VGPRs + asm value-barrier pin
    float4 w0[8], w1[8];
    {
        const float* wp0 = w + (size_t)(gate * 256 + m * 64 + u0) * 256 + kbase;
        const float* wp1 = wp0 + 256;
        #pragma unroll
        for (int i = 0; i < 8; ++i) {
            w0[i] = *(const float4*)(wp0 + i * 4);
            w1[i] = *(const float4*)(wp1 + i * 4);
        }
    }
    #pragma unroll
    for (int i = 0; i < 8; ++i) {
        asm volatile("" : "+v"(w0[i].x), "+v"(w0[i].y), "+v"(w0[i].z), "+v"(w0[i].w));
        asm volatile("" : "+v"(w1[i].x), "+v"(w1[i].y), "+v"(w1[i].z), "+v"(w1[i].w));
    }

    __shared__ __align__(16) float red[2][8][2][256];   // 32 KB, parity-buffered

    // BC mapping (tid<128): wave0 = seq0, wave1 = seq1
    const int s_c = tid >> 6, ul = tid & 63;
    const float* xgp = xg + (size_t)(dir * 64 + b0 + s_c) * 262144 + m * 64 + ul;
    float* hx_w = hx + (size_t)g * 512 + s_c * 256 + m * 64 + ul;     // + par*32768
    float* hc_w = hcat + (size_t)(b0 + s_c) * 131072 + dir * 256 + m * 64 + ul;
    unsigned int* flag_w = flags + ((size_t)g * 4 + m) * 16 + s_c;

    // A mapping: wave-uniform flag + h pointers
    const ull* flag_r = (const ull*)(flags + ((size_t)g * 4 + src) * 16);
    const float* hx_r = hx + (size_t)g * 512 + kbase;                 // + par*32768 (+256 for seq1)

    float c_reg = 0.f;

    for (int t = 0; t < 256; ++t) {
        const int par = t & 1;

        // xg prefetch for BC (issued before poll -> overlaps flag wait + A)
        float xp0 = 0.f, xp1 = 0.f, xp2 = 0.f, xp3 = 0.f;
        if (tid < 128) {
            const float* xq = xgp + (size_t)t * 1024;
            xp0 = xq[0]; xp1 = xq[256]; xp2 = xq[512]; xp3 = xq[768];
        }

        // ---- phase A
        float a00 = 0.f, a01 = 0.f, a10 = 0.f, a11 = 0.f;
        if (t > 0) {
            const unsigned tgt = (unsigned)t;        // need h_{t-1}
            while (true) {
                ull f = __hip_atomic_load(flag_r, __ATOMIC_ACQUIRE, __HIP_MEMORY_SCOPE_AGENT);
                if ((unsigned)f >= tgt && (unsigned)(f >> 32) >= tgt) break;
            }
            const float* hp = hx_r + (size_t)((t - 1) & 1) * 32768;
            #pragma unroll
            for (int j = 0; j < 4; ++j) {            // chunked: k [8j,8j+8)
                float4 h0a = *(const float4*)(hp + j * 8);
                float4 h0b = *(const float4*)(hp + j * 8 + 4);
                float4 h1a = *(const float4*)(hp + 256 + j * 8);
                float4 h1b = *(const float4*)(hp + 256 + j * 8 + 4);
                float4 wa0 = w0[2*j], wa1 = w0[2*j+1];
                float4 wb0 = w1[2*j], wb1 = w1[2*j+1];
                a00 += wa0.x*h0a.x + wa0.y*h0a.y + wa0.z*h0a.z + wa0.w*h0a.w
                     + wa1.x*h0b.x + wa1.y*h0b.y + wa1.z*h0b.z + wa1.w*h0b.w;
                a01 += wa0.x*h1a.x + wa0.y*h1a.y + wa0.z*h1a.z + wa0.w*h1a.w
                     + wa1.x*h1b.x + wa1.y*h1b.y + wa1.z*h1b.z + wa1.w*h1b.w;
                a10 += wb0.x*h0a.x + wb0.y*h0a.y + wb0.z*h0a.z + wb0.w*h0a.w
                     + wb1.x*h0b.x + wb1.y*h0b.y + wb1.z*h0b.z + wb1.w*h0b.w;
                a11 += wb0.x*h1a.x + wb0.y*h1a.y + wb0.z*h1a.z + wb0.w*h1a.w
                     + wb1.x*h1b.x + wb1.y*h1b.y + wb1.z*h1b.z + wb1.w*h1b.w;
            }
        }
        *(float2*)&red[par][kg][0][r0] = make_float2(a00, a10);
        *(float2*)&red[par][kg][1][r0] = make_float2(a01, a11);
        __syncthreads();                                   // the ONLY barrier

        // ---- phase BC (waves 0-1)
        if (tid < 128) {
            float gi = xp0, gf = xp1, gg = xp2, go = xp3;
            #pragma unroll
            for (int kk = 0; kk < 8; ++kk) {
                gi += red[par][kk][s_c][ul];
                gf += red[par][kk][s_c][64 + ul];
                gg += red[par][kk][s_c][128 + ul];
                go += red[par][kk][s_c][192 + ul];
            }
            float si = 1.f / (1.f + expf(-gi));
            float sf = 1.f / (1.f + expf(-gf));
            float so = 1.f / (1.f + expf(-go));
            c_reg = sf * c_reg + si * tanhf(gg);
            float hn = so * tanhf(c_reg);
            __hip_atomic_store(hx_w + (size_t)par * 32768, hn,
                               __ATOMIC_RELAXED, __HIP_MEMORY_SCOPE_AGENT);
            if (ul == 0)     // release waits this wave's vmcnt -> covers its 64 hx stores
                __hip_atomic_store(flag_w, (unsigned)(t + 1),
                                   __ATOMIC_RELEASE, __HIP_MEMORY_SCOPE_AGENT);
            hc_w[(size_t)t * 512] = hn;     // off critical path (fire & forget)
        }
    }
}

// ---------------------------------------------------------------- K3: emissions
__global__ __launch_bounds__(256) void k3_emis(
    const float* __restrict__ hcat, const float* __restrict__ wout,
    const float* __restrict__ bout, const int* __restrict__ lens,
    float* __restrict__ em)
{
    const int b = blockIdx.x >> 3;
    const int tt0 = (blockIdx.x & 7) * 32;
    __shared__ float wsw[512 * 32];
    const int tid = threadIdx.x;
    for (int i = tid; i < 16384; i += 256) {
        int c_ = i >> 9, k_ = i & 511;
        wsw[k_ * 32 + ((k_ + c_) & 31)] = wout[i];
    }
    __syncthreads();
    const int c = tid & 31, tq = tid >> 5;
    const int L = lens[b];
    float acc[4];
    const float* hfp[4];
    const float* hbp[4];
    int tv[4];
    #pragma unroll
    for (int i = 0; i < 4; ++i) {
        int t = tt0 + i * 8 + tq;
        tv[i] = t;
        int tr = (t < L) ? (L - 1 - t) : t;
        hfp[i] = hcat + ((size_t)b * 256 + t) * 512;
        hbp[i] = hcat + ((size_t)b * 256 + tr) * 512 + 256;
        acc[i] = bout[c];
    }
    for (int k = 0; k < 256; k += 4) {
        float w0 = wsw[(k+0)*32 + ((k+0+c)&31)];
        float w1 = wsw[(k+1)*32 + ((k+1+c)&31)];
        float w2_ = wsw[(k+2)*32 + ((k+2+c)&31)];
        float w3 = wsw[(k+3)*32 + ((k+3+c)&31)];
        #pragma unroll
        for (int i = 0; i < 4; ++i) {
            float4 h = *(const float4*)(hfp[i] + k);
            acc[i] += h.x*w0 + h.y*w1 + h.z*w2_ + h.w*w3;
        }
        float v0 = wsw[(256+k+0)*32 + ((256+k+0+c)&31)];
        float v1 = wsw[(256+k+1)*32 + ((256+k+1+c)&31)];
        float v2 = wsw[(256+k+2)*32 + ((256+k+2+c)&31)];
        float v3 = wsw[(256+k+3)*32 + ((256+k+3+c)&31)];
        #pragma unroll
        for (int i = 0; i < 4; ++i) {
            float4 h = *(const float4*)(hbp[i] + k);
            acc[i] += h.x*v0 + h.y*v1 + h.z*v2 + h.w*v3;
        }
    }
    #pragma unroll
    for (int i = 0; i < 4; ++i)
        em[((size_t)b * 256 + tv[i]) * 32 + c] = acc[i];
}

// ---------------------------------------------------------------- K4: Viterbi fwd + backtrace
__global__ __launch_bounds__(256) void k4_viterbi(
    const float* __restrict__ em, const int* __restrict__ lens,
    const float* __restrict__ strans, const float* __restrict__ etrans,
    const float* __restrict__ trans, float* __restrict__ out)
{
    const int b = blockIdx.x;
    __shared__ float em_s[8192];
    __shared__ float trans_t[32 * 33];
    __shared__ float score_s[32];
    __shared__ float fin[32];
    __shared__ unsigned char hist[256][32];
    __shared__ unsigned char path[256];
    __shared__ float bs_s;
    const int tid = threadIdx.x;
    for (int i = tid; i < 8192; i += 256) em_s[i] = em[(size_t)b * 8192 + i];
    for (int i = tid; i < 1024; i += 256) {
        int p = i >> 5, cc = i & 31;
        trans_t[cc * 33 + p] = trans[i];
    }
    __syncthreads();
    if (tid < 32) score_s[tid] = strans[tid] + em_s[tid];
    __syncthreads();
    const int c = tid >> 3, pg = tid & 7;
    const int L = lens[b];
    for (int t = 1; t < 256; ++t) {
        float v = -1e30f; int bi = 0;
        #pragma unroll
        for (int i = 0; i < 4; ++i) {
            int p = pg * 4 + i;
            float cand = score_s[p] + trans_t[c * 33 + p];
            if (cand > v) { v = cand; bi = p; }
        }
        #pragma unroll
        for (int off = 4; off >= 1; off >>= 1) {
            float ov = __shfl_down(v, off);
            int oi = __shfl_down(bi, off);
            if (ov > v) { v = ov; bi = oi; }
        }
        float ns = 0.f;
        if (pg == 0) {
            hist[t][c] = (unsigned char)bi;
            ns = (t < L) ? (v + em_s[t * 32 + c]) : score_s[c];
        }
        __syncthreads();
        if (pg == 0) score_s[c] = ns;
        __syncthreads();
    }
    if (tid < 32) fin[tid] = score_s[tid] + etrans[tid];
    __syncthreads();
    if (tid == 0) {
        float bv = -1e30f; int bl = 0;
        for (int cc = 0; cc < 32; ++cc)
            if (fin[cc] > bv) { bv = fin[cc]; bl = cc; }
        bs_s = bv;
        int tag = bl;
        path[255] = (unsigned char)tag;
        for (int t = 254; t >= 0; --t) {
            if (t < L - 1) tag = hist[t + 1][tag];
            path[t] = (unsigned char)tag;
        }
    }
    __syncthreads();
    out[(size_t)b * 256 + tid] = (float)path[tid];
    if (tid == 0) out[16384 + b] = bs_s;
}

// ---------------------------------------------------------------- launch
extern "C" void kernel_launch(void* const* d_in, const int* in_sizes, int n_in,
                              void* d_out, int out_size, void* d_ws, size_t ws_size,
                              hipStream_t stream)
{
    const int*   sent   = (const int*)  d_in[0];
    const int*   lens   = (const int*)  d_in[1];
    const float* emb    = (const float*)d_in[2];
    const float* wih_f  = (const float*)d_in[3];
    const float* whh_f  = (const float*)d_in[4];
    const float* bih_f  = (const float*)d_in[5];
    const float* bhh_f  = (const float*)d_in[6];
    const float* wih_b  = (const float*)d_in[7];
    const float* whh_b  = (const float*)d_in[8];
    const float* bih_b  = (const float*)d_in[9];
    const float* bhh_b  = (const float*)d_in[10];
    const float* wout   = (const float*)d_in[11];
    const float* bout   = (const float*)d_in[12];
    const float* strans = (const float*)d_in[13];
    const float* etrans = (const float*)d_in[14];
    const float* trans  = (const float*)d_in[15];
    float* out = (float*)d_out;

    float* ws   = (float*)d_ws;
    float* xg   = ws;                        // 33554432
    float* hcat = xg + 33554432;             // 8388608
    float* em   = hcat + 8388608;            // 524288
    float* hx   = em + 524288;               // 65536
    unsigned int* flags = (unsigned int*)(hx + 65536);  // 4096

    hipLaunchKernelGGL(k0z_zero, dim3(4), dim3(1024), 0, stream, flags);
    hipLaunchKernelGGL(k1_xgemm, dim3(2048), dim3(256), 0, stream,
                       sent, lens, emb, wih_f, wih_b, bih_f, bhh_f, bih_b, bhh_b, xg);
    hipLaunchKernelGGL(k2_lstm, dim3(256), dim3(1024), 0, stream,
                       whh_f, whh_b, xg, hcat, hx, flags);
    hipLaunchKernelGGL(k3_emis, dim3(512), dim3(256), 0, stream,
                       hcat, wout, bout, lens, em);
    hipLaunchKernelGGL(k4_viterbi, dim3(64), dim3(256), 0, stream,
                       em, lens, strans, etrans, trans, out);
}

// Round 6
// 2923.161 us; speedup vs baseline: 11.8772x; 11.8772x over previous
//
#include <hip/hip_runtime.h>
#include <math.h>

// BiLSTM-CRF, fp32. V=50000 B=64 T=256 D=256 H=256 C=32
//
// R5: weight-stationary LSTM, one barrier/step. All cross-WG traffic via
// relaxed agent-scope atomics (sc1, coherence-point). NO acquire in hot loop
// (R4's acquire-spin emitted buffer_inv per poll -> L2 wiped continuously ->
// 23x regression). Producer release = s_waitcnt vmcnt(0) + sc1 flag store.
//
// ws layout (floats):
//   xg    : [2][64][256][1024]          33554432
//   hcat  : [64][256][512]               8388608
//   em    : [64][256][32]                 524288
//   hx    : [2buf][64grp][2seq][256]       65536
//   flags : [64grp][4mem][16pad] uint       4096  (dwords 0,1 = seq0,seq1)
//
// d_out: float32[16448] = paths[64][256] (as float) then best_score[64]

typedef unsigned long long ull;

// ---------------------------------------------------------------- K0z: zero flags
__global__ void k0z_zero(unsigned int* __restrict__ flags)
{
    int i = blockIdx.x * 1024 + threadIdx.x;
    if (i < 4096) flags[i] = 0u;
}

// ---------------------------------------------------------------- K1: embed + input GEMM
__global__ __launch_bounds__(256) void k1_xgemm(
    const int* __restrict__ sent, const int* __restrict__ lens,
    const float* __restrict__ emb,
    const float* __restrict__ wih_f, const float* __restrict__ wih_b,
    const float* __restrict__ bih_f, const float* __restrict__ bhh_f,
    const float* __restrict__ bih_b, const float* __restrict__ bhh_b,
    float* __restrict__ xg)
{
    const int bid = blockIdx.x;          // 2048 = 2 dir * 128 mt * 8 nt
    const int dir = bid >> 10;
    const int rem = bid & 1023;
    const int mt = rem >> 3, nt = rem & 7;
    const int r0 = mt * 128, j0 = nt * 128;
    const int b = r0 >> 8, t0 = r0 & 255;
    const float* __restrict__ wih = dir ? wih_b : wih_f;
    const float* __restrict__ bih = dir ? bih_b : bih_f;
    const float* __restrict__ bhh = dir ? bhh_b : bhh_f;

    __shared__ __align__(16) float At[32][132];
    __shared__ __align__(16) float Bt[32][132];
    __shared__ int tok_s[128];

    const int tid = threadIdx.x;
    if (tid < 128) {
        int t = t0 + tid;
        int tt = t;
        if (dir) { int L = lens[b]; if (t < L) tt = L - 1 - t; }
        tok_s[tid] = sent[b * 256 + tt];
    }
    __syncthreads();

    float acc[8][8];
    #pragma unroll
    for (int i = 0; i < 8; ++i)
        #pragma unroll
        for (int j = 0; j < 8; ++j) acc[i][j] = 0.f;

    const int lrow = tid >> 3;
    const int l8 = tid & 7;
    const int tx = tid & 15, ty = tid >> 4;

    for (int kc = 0; kc < 256; kc += 32) {
        #pragma unroll
        for (int it = 0; it < 4; ++it) {
            int row = lrow + it * 32;
            float4 va = *(const float4*)(emb + (size_t)tok_s[row] * 256 + kc + l8 * 4);
            At[l8*4+0][row] = va.x; At[l8*4+1][row] = va.y;
            At[l8*4+2][row] = va.z; At[l8*4+3][row] = va.w;
            float4 vb = *(const float4*)(wih + (size_t)(j0 + row) * 256 + kc + l8 * 4);
            Bt[l8*4+0][row] = vb.x; Bt[l8*4+1][row] = vb.y;
            Bt[l8*4+2][row] = vb.z; Bt[l8*4+3][row] = vb.w;
        }
        __syncthreads();
        #pragma unroll
        for (int k = 0; k < 32; ++k) {
            float4 a0 = *(const float4*)&At[k][ty*8];
            float4 a1 = *(const float4*)&At[k][ty*8+4];
            float4 b0 = *(const float4*)&Bt[k][tx*8];
            float4 b1 = *(const float4*)&Bt[k][tx*8+4];
            float av[8] = {a0.x,a0.y,a0.z,a0.w,a1.x,a1.y,a1.z,a1.w};
            float bv[8] = {b0.x,b0.y,b0.z,b0.w,b1.x,b1.y,b1.z,b1.w};
            #pragma unroll
            for (int i = 0; i < 8; ++i)
                #pragma unroll
                for (int j = 0; j < 8; ++j)
                    acc[i][j] += av[i] * bv[j];
        }
        __syncthreads();
    }

    float bias[8];
    {
        float4 p0 = *(const float4*)(bih + j0 + tx*8);
        float4 p1 = *(const float4*)(bih + j0 + tx*8 + 4);
        float4 q0 = *(const float4*)(bhh + j0 + tx*8);
        float4 q1 = *(const float4*)(bhh + j0 + tx*8 + 4);
        bias[0]=p0.x+q0.x; bias[1]=p0.y+q0.y; bias[2]=p0.z+q0.z; bias[3]=p0.w+q0.w;
        bias[4]=p1.x+q1.x; bias[5]=p1.y+q1.y; bias[6]=p1.z+q1.z; bias[7]=p1.w+q1.w;
    }
    #pragma unroll
    for (int i = 0; i < 8; ++i) {
        int r = r0 + ty*8 + i;
        int t = r & 255;
        float* orow = xg + ((size_t)(dir*64 + b) * 256 + t) * 1024 + j0 + tx*8;
        float4 o0, o1;
        o0.x = acc[i][0]+bias[0]; o0.y = acc[i][1]+bias[1];
        o0.z = acc[i][2]+bias[2]; o0.w = acc[i][3]+bias[3];
        o1.x = acc[i][4]+bias[4]; o1.y = acc[i][5]+bias[5];
        o1.z = acc[i][6]+bias[6]; o1.w = acc[i][7]+bias[7];
        *(float4*)orow = o0;
        *(float4*)(orow + 4) = o1;
    }
}

// ---------------------------------------------------------------- K2: weight-stationary LSTM
// 256 WGs: member m = blockIdx>>6 (64-unit slice), group g = blockIdx&63.
// Wave-pair kg (tid>>7) covers k-units [32kg,32kg+32) -> source member src=kg>>1.
// Step: A(relaxed poll, sc1 atomic h loads in 2 chunks, 128 FMA, red write)
//       -> 1 barrier -> BC(reduce + cell + sc1 hx store + RELEASE flag + hcat).
__global__ __launch_bounds__(1024)
__attribute__((amdgpu_waves_per_eu(4, 4)))
void k2_lstm(
    const float* __restrict__ whh_f, const float* __restrict__ whh_b,
    const float* __restrict__ xg, float* __restrict__ hcat,
    float* __restrict__ hx, unsigned int* __restrict__ flags)
{
    const int m = blockIdx.x >> 6;       // slice / member 0..3
    const int g = blockIdx.x & 63;       // group
    const int dir = g >> 5;
    const int b0 = (g & 31) * 2;
    const float* __restrict__ w = dir ? whh_b : whh_f;

    const int tid = threadIdx.x;
    const int kg = tid >> 7;             // 0..7 wave-pair-uniform
    const int rp = tid & 127;
    const int r0 = rp * 2;               // local rows {r0, r0+1}; r = gate*64+u
    const int gate = r0 >> 6;
    const int u0 = r0 & 63;
    const int kbase = kg * 32;
    const int src = kg >> 1;             // member owning this k-slice

    // ---- weights to VGPRs + asm value-barrier pin (32 k-floats per row)
    float4 w0[8], w1[8];
    {
        const float* wp0 = w + (size_t)(gate * 256 + m * 64 + u0) * 256 + kbase;
        const float* wp1 = wp0 + 256;
        #pragma unroll
        for (int i = 0; i < 8; ++i) {
            w0[i] = *(const float4*)(wp0 + i * 4);
            w1[i] = *(const float4*)(wp1 + i * 4);
        }
    }
    #pragma unroll
    for (int i = 0; i < 8; ++i) {
        asm volatile("" : "+v"(w0[i].x), "+v"(w0[i].y), "+v"(w0[i].z), "+v"(w0[i].w));
        asm volatile("" : "+v"(w1[i].x), "+v"(w1[i].y), "+v"(w1[i].z), "+v"(w1[i].w));
    }
    const float* wf0 = (const float*)w0;   // flat 32-float views (k within slice)
    const float* wf1 = (const float*)w1;

    __shared__ __align__(16) float red[2][8][2][256];   // 32 KB, parity-buffered

    // BC mapping (tid<128): wave0 = seq0, wave1 = seq1
    const int s_c = tid >> 6, ul = tid & 63;
    const float* xgp = xg + (size_t)(dir * 64 + b0 + s_c) * 262144 + m * 64 + ul;
    float* hx_w = hx + (size_t)g * 512 + s_c * 256 + m * 64 + ul;     // + par*32768
    float* hc_w = hcat + (size_t)(b0 + s_c) * 131072 + dir * 256 + m * 64 + ul;
    unsigned int* flag_w = flags + ((size_t)g * 4 + m) * 16 + s_c;

    // A mapping: wave-uniform flag + h base (ull units)
    const ull* flag_r = (const ull*)(flags + ((size_t)g * 4 + src) * 16);
    const ull* hx_r8 = (const ull*)(hx + (size_t)g * 512) + (kbase >> 1);  // seq1: +128 ull; par: +16384 ull

    float c_reg = 0.f;

    for (int t = 0; t < 256; ++t) {
        const int par = t & 1;

        // xg prefetch for BC (overlaps poll + A)
        float xp0 = 0.f, xp1 = 0.f, xp2 = 0.f, xp3 = 0.f;
        if (tid < 128) {
            const float* xq = xgp + (size_t)t * 1024;
            xp0 = xq[0]; xp1 = xq[256]; xp2 = xq[512]; xp3 = xq[768];
        }

        // ---- phase A
        float a00 = 0.f, a01 = 0.f, a10 = 0.f, a11 = 0.f;
        if (t > 0) {
            const unsigned tgt = (unsigned)t;        // need h_{t-1}
            while (true) {                           // RELAXED poll: no cache maintenance
                ull f = __hip_atomic_load(flag_r, __ATOMIC_RELAXED, __HIP_MEMORY_SCOPE_AGENT);
                if ((unsigned)f >= tgt && (unsigned)(f >> 32) >= tgt) break;
            }
            const ull* hp8 = hx_r8 + (size_t)((t - 1) & 1) * 16384;
            #pragma unroll
            for (int ch = 0; ch < 2; ++ch) {         // 2 chunks x 16 ull: liveness <= 32 VGPR
                ull u0v[8], u1v[8];
                #pragma unroll
                for (int i = 0; i < 8; ++i) {
                    u0v[i] = __hip_atomic_load(hp8 + ch * 8 + i,
                                               __ATOMIC_RELAXED, __HIP_MEMORY_SCOPE_AGENT);
                    u1v[i] = __hip_atomic_load(hp8 + 128 + ch * 8 + i,
                                               __ATOMIC_RELAXED, __HIP_MEMORY_SCOPE_AGENT);
                }
                #pragma unroll
                for (int i = 0; i < 8; ++i) {
                    union { ull u; float2 f; } x0, x1;
                    x0.u = u0v[i]; x1.u = u1v[i];
                    const int kk = ch * 16 + i * 2;   // k, k+1 within slice
                    float wa0 = wf0[kk], wa1 = wf0[kk + 1];
                    float wb0 = wf1[kk], wb1 = wf1[kk + 1];
                    a00 += wa0 * x0.f.x + wa1 * x0.f.y;
                    a01 += wa0 * x1.f.x + wa1 * x1.f.y;
                    a10 += wb0 * x0.f.x + wb1 * x0.f.y;
                    a11 += wb0 * x1.f.x + wb1 * x1.f.y;
                }
            }
        }
        *(float2*)&red[par][kg][0][r0] = make_float2(a00, a10);
        *(float2*)&red[par][kg][1][r0] = make_float2(a01, a11);
        __syncthreads();                                   // the ONLY barrier

        // ---- phase BC (waves 0-1)
        if (tid < 128) {
            float gi = xp0, gf = xp1, gg = xp2, go = xp3;
            #pragma unroll
            for (int kk = 0; kk < 8; ++kk) {
                gi += red[par][kk][s_c][ul];
                gf += red[par][kk][s_c][64 + ul];
                gg += red[par][kk][s_c][128 + ul];
                go += red[par][kk][s_c][192 + ul];
            }
            float si = 1.f / (1.f + expf(-gi));
            float sf = 1.f / (1.f + expf(-gf));
            float so = 1.f / (1.f + expf(-go));
            c_reg = sf * c_reg + si * tanhf(gg);
            float hn = so * tanhf(c_reg);
            __hip_atomic_store(hx_w + (size_t)par * 32768, hn,
                               __ATOMIC_RELAXED, __HIP_MEMORY_SCOPE_AGENT);
            if (ul == 0)     // RELEASE: s_waitcnt vmcnt(0) covers this wave's 64 hx stores
                __hip_atomic_store(flag_w, (unsigned)(t + 1),
                                   __ATOMIC_RELEASE, __HIP_MEMORY_SCOPE_AGENT);
            hc_w[(size_t)t * 512] = hn;     // off critical path (fire & forget)
        }
    }
}

// ---------------------------------------------------------------- K3: emissions
__global__ __launch_bounds__(256) void k3_emis(
    const float* __restrict__ hcat, const float* __restrict__ wout,
    const float* __restrict__ bout, const int* __restrict__ lens,
    float* __restrict__ em)
{
    const int b = blockIdx.x >> 3;
    const int tt0 = (blockIdx.x & 7) * 32;
    __shared__ float wsw[512 * 32];
    const int tid = threadIdx.x;
    for (int i = tid; i < 16384; i += 256) {
        int c_ = i >> 9, k_ = i & 511;
        wsw[k_ * 32 + ((k_ + c_) & 31)] = wout[i];
    }
    __syncthreads();
    const int c = tid & 31, tq = tid >> 5;
    const int L = lens[b];
    float acc[4];
    const float* hfp[4];
    const float* hbp[4];
    int tv[4];
    #pragma unroll
    for (int i = 0; i < 4; ++i) {
        int t = tt0 + i * 8 + tq;
        tv[i] = t;
        int tr = (t < L) ? (L - 1 - t) : t;
        hfp[i] = hcat + ((size_t)b * 256 + t) * 512;
        hbp[i] = hcat + ((size_t)b * 256 + tr) * 512 + 256;
        acc[i] = bout[c];
    }
    for (int k = 0; k < 256; k += 4) {
        float w0 = wsw[(k+0)*32 + ((k+0+c)&31)];
        float w1 = wsw[(k+1)*32 + ((k+1+c)&31)];
        float w2_ = wsw[(k+2)*32 + ((k+2+c)&31)];
        float w3 = wsw[(k+3)*32 + ((k+3+c)&31)];
        #pragma unroll
        for (int i = 0; i < 4; ++i) {
            float4 h = *(const float4*)(hfp[i] + k);
            acc[i] += h.x*w0 + h.y*w1 + h.z*w2_ + h.w*w3;
        }
        float v0 = wsw[(256+k+0)*32 + ((256+k+0+c)&31)];
        float v1 = wsw[(256+k+1)*32 + ((256+k+1+c)&31)];
        float v2 = wsw[(256+k+2)*32 + ((256+k+2+c)&31)];
        float v3 = wsw[(256+k+3)*32 + ((256+k+3+c)&31)];
        #pragma unroll
        for (int i = 0; i < 4; ++i) {
            float4 h = *(const float4*)(hbp[i] + k);
            acc[i] += h.x*v0 + h.y*v1 + h.z*v2 + h.w*v3;
        }
    }
    #pragma unroll
    for (int i = 0; i < 4; ++i)
        em[((size_t)b * 256 + tv[i]) * 32 + c] = acc[i];
}

// ---------------------------------------------------------------- K4: Viterbi fwd + backtrace
__global__ __launch_bounds__(256) void k4_viterbi(
    const float* __restrict__ em, const int* __restrict__ lens,
    const float* __restrict__ strans, const float* __restrict__ etrans,
    const float* __restrict__ trans, float* __restrict__ out)
{
    const int b = blockIdx.x;
    __shared__ float em_s[8192];
    __shared__ float trans_t[32 * 33];
    __shared__ float score_s[32];
    __shared__ float fin[32];
    __shared__ unsigned char hist[256][32];
    __shared__ unsigned char path[256];
    __shared__ float bs_s;
    const int tid = threadIdx.x;
    for (int i = tid; i < 8192; i += 256) em_s[i] = em[(size_t)b * 8192 + i];
    for (int i = tid; i < 1024; i += 256) {
        int p = i >> 5, cc = i & 31;
        trans_t[cc * 33 + p] = trans[i];
    }
    __syncthreads();
    if (tid < 32) score_s[tid] = strans[tid] + em_s[tid];
    __syncthreads();
    const int c = tid >> 3, pg = tid & 7;
    const int L = lens[b];
    for (int t = 1; t < 256; ++t) {
        float v = -1e30f; int bi = 0;
        #pragma unroll
        for (int i = 0; i < 4; ++i) {
            int p = pg * 4 + i;
            float cand = score_s[p] + trans_t[c * 33 + p];
            if (cand > v) { v = cand; bi = p; }
        }
        #pragma unroll
        for (int off = 4; off >= 1; off >>= 1) {
            float ov = __shfl_down(v, off);
            int oi = __shfl_down(bi, off);
            if (ov > v) { v = ov; bi = oi; }
        }
        float ns = 0.f;
        if (pg == 0) {
            hist[t][c] = (unsigned char)bi;
            ns = (t < L) ? (v + em_s[t * 32 + c]) : score_s[c];
        }
        __syncthreads();
        if (pg == 0) score_s[c] = ns;
        __syncthreads();
    }
    if (tid < 32) fin[tid] = score_s[tid] + etrans[tid];
    __syncthreads();
    if (tid == 0) {
        float bv = -1e30f; int bl = 0;
        for (int cc = 0; cc < 32; ++cc)
            if (fin[cc] > bv) { bv = fin[cc]; bl = cc; }
        bs_s = bv;
        int tag = bl;
        path[255] = (unsigned char)tag;
        for (int t = 254; t >= 0; --t) {
            if (t < L - 1) tag = hist[t + 1][tag];
            path[t] = (unsigned char)tag;
        }
    }
    __syncthreads();
    out[(size_t)b * 256 + tid] = (float)path[tid];
    if (tid == 0) out[16384 + b] = bs_s;
}

// ---------------------------------------------------------------- launch
extern "C" void kernel_launch(void* const* d_in, const int* in_sizes, int n_in,
                              void* d_out, int out_size, void* d_ws, size_t ws_size,
                              hipStream_t stream)
{
    const int*   sent   = (const int*)  d_in[0];
    const int*   lens   = (const int*)  d_in[1];
    const float* emb    = (const float*)d_in[2];
    const float* wih_f  = (const float*)d_in[3];
    const float* whh_f  = (const float*)d_in[4];
    const float* bih_f  = (const float*)d_in[5];
    const float* bhh_f  = (const float*)d_in[6];
    const float* wih_b  = (const float*)d_in[7];
    const float* whh_b  = (const float*)d_in[8];
    const float* bih_b  = (const float*)d_in[9];
    const float* bhh_b  = (const float*)d_in[10];
    const float* wout   = (const float*)d_in[11];
    const float* bout   = (const float*)d_in[12];
    const float* strans = (const float*)d_in[13];
    const float* etrans = (const float*)d_in[14];
    const float* trans  = (const float*)d_in[15];
    float* out = (float*)d_out;

    float* ws   = (float*)d_ws;
    float* xg   = ws;                        // 33554432
    float* hcat = xg + 33554432;             // 8388608
    float* em   = hcat + 8388608;            // 524288
    float* hx   = em + 524288;               // 65536
    unsigned int* flags = (unsigned int*)(hx + 65536);  // 4096

    hipLaunchKernelGGL(k0z_zero, dim3(4), dim3(1024), 0, stream, flags);
    hipLaunchKernelGGL(k1_xgemm, dim3(2048), dim3(256), 0, stream,
                       sent, lens, emb, wih_f, wih_b, bih_f, bhh_f, bih_b, bhh_b, xg);
    hipLaunchKernelGGL(k2_lstm, dim3(256), dim3(1024), 0, stream,
                       whh_f, whh_b, xg, hcat, hx, flags);
    hipLaunchKernelGGL(k3_emis, dim3(512), dim3(256), 0, stream,
                       hcat, wout, bout, lens, em);
    hipLaunchKernelGGL(k4_viterbi, dim3(64), dim3(256), 0, stream,
                       em, lens, strans, etrans, trans, out);
}

// Round 7
// 1943.837 us; speedup vs baseline: 17.8610x; 1.5038x over previous
//
#include <hip/hip_runtime.h>
#include <math.h>

// BiLSTM-CRF, fp32. V=50000 B=64 T=256 D=256 H=256 C=32
//
// R6: weight-stationary LSTM, 512-thr WGs (128 w/thread, waves_per_eu(2,2)),
// 2 barriers/step, BC || loader in parallel waves. Exchange: relaxed sc1
// stores + release flag (producer) / relaxed per-lane poll + ONE coalesced
// relaxed sc1 ull load per lane (consumer). 80KB LDS pad = 1 WG/CU.
//
// ws layout (floats):
//   xg    : [2][64][256][1024]          33554432
//   hcat  : [64][256][512]               8388608
//   em    : [64][256][32]                 524288
//   hx    : [2buf][64grp][2seq][256]       65536
//   flags : [64grp][4mem][16pad] uint       4096  (dwords 0,1 = seq0,seq1)
//
// d_out: float32[16448] = paths[64][256] (as float) then best_score[64]

typedef unsigned long long ull;

// ---------------------------------------------------------------- K0z: zero flags
__global__ void k0z_zero(unsigned int* __restrict__ flags)
{
    int i = blockIdx.x * 1024 + threadIdx.x;
    if (i < 4096) flags[i] = 0u;
}

// ---------------------------------------------------------------- K1: embed + input GEMM
__global__ __launch_bounds__(256) void k1_xgemm(
    const int* __restrict__ sent, const int* __restrict__ lens,
    const float* __restrict__ emb,
    const float* __restrict__ wih_f, const float* __restrict__ wih_b,
    const float* __restrict__ bih_f, const float* __restrict__ bhh_f,
    const float* __restrict__ bih_b, const float* __restrict__ bhh_b,
    float* __restrict__ xg)
{
    const int bid = blockIdx.x;          // 2048 = 2 dir * 128 mt * 8 nt
    const int dir = bid >> 10;
    const int rem = bid & 1023;
    const int mt = rem >> 3, nt = rem & 7;
    const int r0 = mt * 128, j0 = nt * 128;
    const int b = r0 >> 8, t0 = r0 & 255;
    const float* __restrict__ wih = dir ? wih_b : wih_f;
    const float* __restrict__ bih = dir ? bih_b : bih_f;
    const float* __restrict__ bhh = dir ? bhh_b : bhh_f;

    __shared__ __align__(16) float At[32][132];
    __shared__ __align__(16) float Bt[32][132];
    __shared__ int tok_s[128];

    const int tid = threadIdx.x;
    if (tid < 128) {
        int t = t0 + tid;
        int tt = t;
        if (dir) { int L = lens[b]; if (t < L) tt = L - 1 - t; }
        tok_s[tid] = sent[b * 256 + tt];
    }
    __syncthreads();

    float acc[8][8];
    #pragma unroll
    for (int i = 0; i < 8; ++i)
        #pragma unroll
        for (int j = 0; j < 8; ++j) acc[i][j] = 0.f;

    const int lrow = tid >> 3;
    const int l8 = tid & 7;
    const int tx = tid & 15, ty = tid >> 4;

    for (int kc = 0; kc < 256; kc += 32) {
        #pragma unroll
        for (int it = 0; it < 4; ++it) {
            int row = lrow + it * 32;
            float4 va = *(const float4*)(emb + (size_t)tok_s[row] * 256 + kc + l8 * 4);
            At[l8*4+0][row] = va.x; At[l8*4+1][row] = va.y;
            At[l8*4+2][row] = va.z; At[l8*4+3][row] = va.w;
            float4 vb = *(const float4*)(wih + (size_t)(j0 + row) * 256 + kc + l8 * 4);
            Bt[l8*4+0][row] = vb.x; Bt[l8*4+1][row] = vb.y;
            Bt[l8*4+2][row] = vb.z; Bt[l8*4+3][row] = vb.w;
        }
        __syncthreads();
        #pragma unroll
        for (int k = 0; k < 32; ++k) {
            float4 a0 = *(const float4*)&At[k][ty*8];
            float4 a1 = *(const float4*)&At[k][ty*8+4];
            float4 b0 = *(const float4*)&Bt[k][tx*8];
            float4 b1 = *(const float4*)&Bt[k][tx*8+4];
            float av[8] = {a0.x,a0.y,a0.z,a0.w,a1.x,a1.y,a1.z,a1.w};
            float bv[8] = {b0.x,b0.y,b0.z,b0.w,b1.x,b1.y,b1.z,b1.w};
            #pragma unroll
            for (int i = 0; i < 8; ++i)
                #pragma unroll
                for (int j = 0; j < 8; ++j)
                    acc[i][j] += av[i] * bv[j];
        }
        __syncthreads();
    }

    float bias[8];
    {
        float4 p0 = *(const float4*)(bih + j0 + tx*8);
        float4 p1 = *(const float4*)(bih + j0 + tx*8 + 4);
        float4 q0 = *(const float4*)(bhh + j0 + tx*8);
        float4 q1 = *(const float4*)(bhh + j0 + tx*8 + 4);
        bias[0]=p0.x+q0.x; bias[1]=p0.y+q0.y; bias[2]=p0.z+q0.z; bias[3]=p0.w+q0.w;
        bias[4]=p1.x+q1.x; bias[5]=p1.y+q1.y; bias[6]=p1.z+q1.z; bias[7]=p1.w+q1.w;
    }
    #pragma unroll
    for (int i = 0; i < 8; ++i) {
        int r = r0 + ty*8 + i;
        int t = r & 255;
        float* orow = xg + ((size_t)(dir*64 + b) * 256 + t) * 1024 + j0 + tx*8;
        float4 o0, o1;
        o0.x = acc[i][0]+bias[0]; o0.y = acc[i][1]+bias[1];
        o0.z = acc[i][2]+bias[2]; o0.w = acc[i][3]+bias[3];
        o1.x = acc[i][4]+bias[4]; o1.y = acc[i][5]+bias[5];
        o1.z = acc[i][6]+bias[6]; o1.w = acc[i][7]+bias[7];
        *(float4*)orow = o0;
        *(float4*)(orow + 4) = o1;
    }
}

// ---------------------------------------------------------------- K2: weight-stationary LSTM
// 256 WGs x 512 thr: member m = blockIdx>>6 (64-unit slice), group g = blockIdx&63.
// Thread (kg=tid>>6, q=tid&63): 4 rows {gate=q>>4, units (q&15)*4..+3} x k[kg*32,+32)
// = 128 weights in VGPRs. Step: A(LDS hs read, 256 FMA, red write) -> b1 ->
// {BC: reduce+cell+hx(sc1)+flag(release) || loader: per-lane poll + 1 ull sc1
// load + hs/hcat write} -> b2.
__global__ __launch_bounds__(512)
__attribute__((amdgpu_waves_per_eu(2, 2)))
void k2_lstm(
    const float* __restrict__ whh_f, const float* __restrict__ whh_b,
    const float* __restrict__ xg, float* __restrict__ hcat,
    float* __restrict__ hx, unsigned int* __restrict__ flags)
{
    const int m = blockIdx.x >> 6;       // slice / member 0..3
    const int g = blockIdx.x & 63;       // group
    const int dir = g >> 5;
    const int b0 = (g & 31) * 2;
    const float* __restrict__ w = dir ? whh_b : whh_f;

    const int tid = threadIdx.x;
    const int kg = tid >> 6;             // 0..7 (wave-uniform)
    const int q  = tid & 63;
    const int gate = q >> 4;             // 0..3
    const int u0 = (q & 15) * 4;         // unit quad base
    const int kbase = kg * 32;
    const int j0 = gate * 256 + m * 64 + u0;   // global row base (4 rows)

    // ---- 128 weights -> VGPRs, pinned with asm value barriers
    float4 wv[4][8];
    #pragma unroll
    for (int j = 0; j < 4; ++j) {
        const float* wp = w + (size_t)(j0 + j) * 256 + kbase;
        #pragma unroll
        for (int i = 0; i < 8; ++i)
            wv[j][i] = *(const float4*)(wp + i * 4);
    }
    #pragma unroll
    for (int j = 0; j < 4; ++j)
        #pragma unroll
        for (int i = 0; i < 8; ++i)
            asm volatile("" : "+v"(wv[j][i].x), "+v"(wv[j][i].y),
                              "+v"(wv[j][i].z), "+v"(wv[j][i].w));

    __shared__ __align__(16) float hs[2][256];        // h_{t-1}, both seqs
    __shared__ __align__(16) float red[8][2][256];    // 16 KB partials
    __shared__ float ldspad[20480];                   // 80 KB: forces 1 WG/CU
    if (blockIdx.x == 99999u) ldspad[tid] = 1.f;      // never true (grid=256)

    // BC mapping (tid<128): wave0 = seq0, wave1 = seq1
    const int s_c = tid >> 6, ul = tid & 63;
    const float* xgp = xg + (size_t)(dir * 64 + b0 + s_c) * 262144
                          + gate * 0 + m * 64 + ul;   // + t*1024 + gate*256
    float* hx_w = hx + (size_t)g * 512 + s_c * 256 + m * 64 + ul;   // + par*32768
    unsigned int* flag_w = flags + ((size_t)g * 4 + m) * 16 + s_c;

    // loader mapping (tid in [256,512)): 256 threads, 2 floats each
    const int tid2 = tid - 256;                       // 0..255 (valid when tid>=256)
    const int s_r = (tid2 >> 7) & 1, pr = tid2 & 127;
    const int src = pr >> 5;                          // member owning units [2pr,2pr+1]
    const unsigned int* flag_r = flags + ((size_t)g * 4 + src) * 16 + s_r;
    const ull* hx_r = (const ull*)(hx + (size_t)g * 512 + s_r * 256) + pr; // + par*16384
    float* hc_r = hcat + (size_t)(b0 + s_r) * 131072 + dir * 256 + 2 * pr; // + t*512

    ((float*)hs)[tid & 511] = 0.f;       // zero 512 entries
    float c_reg = 0.f;
    __syncthreads();

    for (int t = 0; t < 256; ++t) {
        const int par = t & 1;

        // xg prefetch for BC (issued pre-A, latency hidden under A)
        float xp0 = 0.f, xp1 = 0.f, xp2 = 0.f, xp3 = 0.f;
        if (tid < 128) {
            const float* xq = xgp + (size_t)t * 1024;
            xp0 = xq[0]; xp1 = xq[256]; xp2 = xq[512]; xp3 = xq[768];
        }

        // ---- phase A: 4 rows x 2 seqs x 32 k from register weights
        float a0s0 = 0.f, a1s0 = 0.f, a2s0 = 0.f, a3s0 = 0.f;
        float a0s1 = 0.f, a1s1 = 0.f, a2s1 = 0.f, a3s1 = 0.f;
        #pragma unroll
        for (int i = 0; i < 8; ++i) {
            float4 ha = *(const float4*)&hs[0][kbase + i * 4];   // broadcast
            float4 hb = *(const float4*)&hs[1][kbase + i * 4];
            float4 w0 = wv[0][i], w1 = wv[1][i], w2 = wv[2][i], w3 = wv[3][i];
            a0s0 += w0.x*ha.x + w0.y*ha.y + w0.z*ha.z + w0.w*ha.w;
            a1s0 += w1.x*ha.x + w1.y*ha.y + w1.z*ha.z + w1.w*ha.w;
            a2s0 += w2.x*ha.x + w2.y*ha.y + w2.z*ha.z + w2.w*ha.w;
            a3s0 += w3.x*ha.x + w3.y*ha.y + w3.z*ha.z + w3.w*ha.w;
            a0s1 += w0.x*hb.x + w0.y*hb.y + w0.z*hb.z + w0.w*hb.w;
            a1s1 += w1.x*hb.x + w1.y*hb.y + w1.z*hb.z + w1.w*hb.w;
            a2s1 += w2.x*hb.x + w2.y*hb.y + w2.z*hb.z + w2.w*hb.w;
            a3s1 += w3.x*hb.x + w3.y*hb.y + w3.z*hb.z + w3.w*hb.w;
        }
        float4 r0v; r0v.x = a0s0; r0v.y = a1s0; r0v.z = a2s0; r0v.w = a3s0;
        float4 r1v; r1v.x = a0s1; r1v.y = a1s1; r1v.z = a2s1; r1v.w = a3s1;
        *(float4*)&red[kg][0][q * 4] = r0v;     // rows gate*64 + u0..u0+3
        *(float4*)&red[kg][1][q * 4] = r1v;
        __syncthreads();                                   // b1

        // ---- phase BC (waves 0-1)  ||  loader (waves 4-7)
        if (tid < 128) {
            float gi = xp0, gf = xp1, gg = xp2, go = xp3;
            #pragma unroll
            for (int kk = 0; kk < 8; ++kk) {
                gi += red[kk][s_c][ul];            // gate 0 rows [0,64)
                gf += red[kk][s_c][64 + ul];
                gg += red[kk][s_c][128 + ul];
                go += red[kk][s_c][192 + ul];
            }
            float si = 1.f / (1.f + expf(-gi));
            float sf = 1.f / (1.f + expf(-gf));
            float so = 1.f / (1.f + expf(-go));
            c_reg = sf * c_reg + si * tanhf(gg);
            float hn = so * tanhf(c_reg);
            __hip_atomic_store(hx_w + (size_t)par * 32768, hn,
                               __ATOMIC_RELAXED, __HIP_MEMORY_SCOPE_AGENT);
            if (ul == 0)   // release: s_waitcnt vmcnt(0) covers this wave's 64 stores
                __hip_atomic_store(flag_w, (unsigned)(t + 1),
                                   __ATOMIC_RELEASE, __HIP_MEMORY_SCOPE_AGENT);
        } else if (tid >= 256) {
            const unsigned tgt = (unsigned)(t + 1);
            while (__hip_atomic_load(flag_r, __ATOMIC_RELAXED,
                                     __HIP_MEMORY_SCOPE_AGENT) < tgt) {}
            ull dv = __hip_atomic_load(hx_r + (size_t)par * 16384,
                                       __ATOMIC_RELAXED, __HIP_MEMORY_SCOPE_AGENT);
            union { ull u; float2 f; } cv; cv.u = dv;
            *(float2*)&hs[s_r][2 * pr] = cv.f;
            *(float2*)(hc_r + (size_t)t * 512) = cv.f;   // fire & forget
        }
        __syncthreads();                                   // b2
    }
}

// ---------------------------------------------------------------- K3: emissions
__global__ __launch_bounds__(256) void k3_emis(
    const float* __restrict__ hcat, const float* __restrict__ wout,
    const float* __restrict__ bout, const int* __restrict__ lens,
    float* __restrict__ em)
{
    const int b = blockIdx.x >> 3;
    const int tt0 = (blockIdx.x & 7) * 32;
    __shared__ float wsw[512 * 32];
    const int tid = threadIdx.x;
    for (int i = tid; i < 16384; i += 256) {
        int c_ = i >> 9, k_ = i & 511;
        wsw[k_ * 32 + ((k_ + c_) & 31)] = wout[i];
    }
    __syncthreads();
    const int c = tid & 31, tq = tid >> 5;
    const int L = lens[b];
    float acc[4];
    const float* hfp[4];
    const float* hbp[4];
    int tv[4];
    #pragma unroll
    for (int i = 0; i < 4; ++i) {
        int t = tt0 + i * 8 + tq;
        tv[i] = t;
        int tr = (t < L) ? (L - 1 - t) : t;
        hfp[i] = hcat + ((size_t)b * 256 + t) * 512;
        hbp[i] = hcat + ((size_t)b * 256 + tr) * 512 + 256;
        acc[i] = bout[c];
    }
    for (int k = 0; k < 256; k += 4) {
        float w0 = wsw[(k+0)*32 + ((k+0+c)&31)];
        float w1 = wsw[(k+1)*32 + ((k+1+c)&31)];
        float w2_ = wsw[(k+2)*32 + ((k+2+c)&31)];
        float w3 = wsw[(k+3)*32 + ((k+3+c)&31)];
        #pragma unroll
        for (int i = 0; i < 4; ++i) {
            float4 h = *(const float4*)(hfp[i] + k);
            acc[i] += h.x*w0 + h.y*w1 + h.z*w2_ + h.w*w3;
        }
        float v0 = wsw[(256+k+0)*32 + ((256+k+0+c)&31)];
        float v1 = wsw[(256+k+1)*32 + ((256+k+1+c)&31)];
        float v2 = wsw[(256+k+2)*32 + ((256+k+2+c)&31)];
        float v3 = wsw[(256+k+3)*32 + ((256+k+3+c)&31)];
        #pragma unroll
        for (int i = 0; i < 4; ++i) {
            float4 h = *(const float4*)(hbp[i] + k);
            acc[i] += h.x*v0 + h.y*v1 + h.z*v2 + h.w*v3;
        }
    }
    #pragma unroll
    for (int i = 0; i < 4; ++i)
        em[((size_t)b * 256 + tv[i]) * 32 + c] = acc[i];
}

// ---------------------------------------------------------------- K4: Viterbi fwd + backtrace
__global__ __launch_bounds__(256) void k4_viterbi(
    const float* __restrict__ em, const int* __restrict__ lens,
    const float* __restrict__ strans, const float* __restrict__ etrans,
    const float* __restrict__ trans, float* __restrict__ out)
{
    const int b = blockIdx.x;
    __shared__ float em_s[8192];
    __shared__ float trans_t[32 * 33];
    __shared__ float score_s[32];
    __shared__ float fin[32];
    __shared__ unsigned char hist[256][32];
    __shared__ unsigned char path[256];
    __shared__ float bs_s;
    const int tid = threadIdx.x;
    for (int i = tid; i < 8192; i += 256) em_s[i] = em[(size_t)b * 8192 + i];
    for (int i = tid; i < 1024; i += 256) {
        int p = i >> 5, cc = i & 31;
        trans_t[cc * 33 + p] = trans[i];
    }
    __syncthreads();
    if (tid < 32) score_s[tid] = strans[tid] + em_s[tid];
    __syncthreads();
    const int c = tid >> 3, pg = tid & 7;
    const int L = lens[b];
    for (int t = 1; t < 256; ++t) {
        float v = -1e30f; int bi = 0;
        #pragma unroll
        for (int i = 0; i < 4; ++i) {
            int p = pg * 4 + i;
            float cand = score_s[p] + trans_t[c * 33 + p];
            if (cand > v) { v = cand; bi = p; }
        }
        #pragma unroll
        for (int off = 4; off >= 1; off >>= 1) {
            float ov = __shfl_down(v, off);
            int oi = __shfl_down(bi, off);
            if (ov > v) { v = ov; bi = oi; }
        }
        float ns = 0.f;
        if (pg == 0) {
            hist[t][c] = (unsigned char)bi;
            ns = (t < L) ? (v + em_s[t * 32 + c]) : score_s[c];
        }
        __syncthreads();
        if (pg == 0) score_s[c] = ns;
        __syncthreads();
    }
    if (tid < 32) fin[tid] = score_s[tid] + etrans[tid];
    __syncthreads();
    if (tid == 0) {
        float bv = -1e30f; int bl = 0;
        for (int cc = 0; cc < 32; ++cc)
            if (fin[cc] > bv) { bv = fin[cc]; bl = cc; }
        bs_s = bv;
        int tag = bl;
        path[255] = (unsigned char)tag;
        for (int t = 254; t >= 0; --t) {
            if (t < L - 1) tag = hist[t + 1][tag];
            path[t] = (unsigned char)tag;
        }
    }
    __syncthreads();
    out[(size_t)b * 256 + tid] = (float)path[tid];
    if (tid == 0) out[16384 + b] = bs_s;
}

// ---------------------------------------------------------------- launch
extern "C" void kernel_launch(void* const* d_in, const int* in_sizes, int n_in,
                              void* d_out, int out_size, void* d_ws, size_t ws_size,
                              hipStream_t stream)
{
    const int*   sent   = (const int*)  d_in[0];
    const int*   lens   = (const int*)  d_in[1];
    const float* emb    = (const float*)d_in[2];
    const float* wih_f  = (const float*)d_in[3];
    const float* whh_f  = (const float*)d_in[4];
    const float* bih_f  = (const float*)d_in[5];
    const float* bhh_f  = (const float*)d_in[6];
    const float* wih_b  = (const float*)d_in[7];
    const float* whh_b  = (const float*)d_in[8];
    const float* bih_b  = (const float*)d_in[9];
    const float* bhh_b  = (const float*)d_in[10];
    const float* wout   = (const float*)d_in[11];
    const float* bout   = (const float*)d_in[12];
    const float* strans = (const float*)d_in[13];
    const float* etrans = (const float*)d_in[14];
    const float* trans  = (const float*)d_in[15];
    float* out = (float*)d_out;

    float* ws   = (float*)d_ws;
    float* xg   = ws;                        // 33554432
    float* hcat = xg + 33554432;             // 8388608
    float* em   = hcat + 8388608;            // 524288
    float* hx   = em + 524288;               // 65536
    unsigned int* flags = (unsigned int*)(hx + 65536);  // 4096

    hipLaunchKernelGGL(k0z_zero, dim3(4), dim3(1024), 0, stream, flags);
    hipLaunchKernelGGL(k1_xgemm, dim3(2048), dim3(256), 0, stream,
                       sent, lens, emb, wih_f, wih_b, bih_f, bhh_f, bih_b, bhh_b, xg);
    hipLaunchKernelGGL(k2_lstm, dim3(256), dim3(512), 0, stream,
                       whh_f, whh_b, xg, hcat, hx, flags);
    hipLaunchKernelGGL(k3_emis, dim3(512), dim3(256), 0, stream,
                       hcat, wout, bout, lens, em);
    hipLaunchKernelGGL(k4_viterbi, dim3(64), dim3(256), 0, stream,
                       em, lens, strans, etrans, trans, out);
}

// Round 8
// 1924.693 us; speedup vs baseline: 18.0386x; 1.0099x over previous
//
#include <hip/hip_runtime.h>
#include <math.h>

// BiLSTM-CRF, fp32. V=50000 B=64 T=256 D=256 H=256 C=32
//
// R7 = R6 + s_sleep(1) poll backoff (R6's 65k unthrottled spinning lanes
// flooded the coherence point ~100 req/cy; producer flag/data writes queued
// behind the poll flood -> 12.6k cy/step of wait).
//
// ws layout (floats):
//   xg    : [2][64][256][1024]          33554432
//   hcat  : [64][256][512]               8388608
//   em    : [64][256][32]                 524288
//   hx    : [2buf][64grp][2seq][256]       65536
//   flags : [64grp][4mem][16pad] uint       4096  (dwords 0,1 = seq0,seq1)
//
// d_out: float32[16448] = paths[64][256] (as float) then best_score[64]

typedef unsigned long long ull;

// ---------------------------------------------------------------- K0z: zero flags
__global__ void k0z_zero(unsigned int* __restrict__ flags)
{
    int i = blockIdx.x * 1024 + threadIdx.x;
    if (i < 4096) flags[i] = 0u;
}

// ---------------------------------------------------------------- K1: embed + input GEMM
__global__ __launch_bounds__(256) void k1_xgemm(
    const int* __restrict__ sent, const int* __restrict__ lens,
    const float* __restrict__ emb,
    const float* __restrict__ wih_f, const float* __restrict__ wih_b,
    const float* __restrict__ bih_f, const float* __restrict__ bhh_f,
    const float* __restrict__ bih_b, const float* __restrict__ bhh_b,
    float* __restrict__ xg)
{
    const int bid = blockIdx.x;          // 2048 = 2 dir * 128 mt * 8 nt
    const int dir = bid >> 10;
    const int rem = bid & 1023;
    const int mt = rem >> 3, nt = rem & 7;
    const int r0 = mt * 128, j0 = nt * 128;
    const int b = r0 >> 8, t0 = r0 & 255;
    const float* __restrict__ wih = dir ? wih_b : wih_f;
    const float* __restrict__ bih = dir ? bih_b : bih_f;
    const float* __restrict__ bhh = dir ? bhh_b : bhh_f;

    __shared__ __align__(16) float At[32][132];
    __shared__ __align__(16) float Bt[32][132];
    __shared__ int tok_s[128];

    const int tid = threadIdx.x;
    if (tid < 128) {
        int t = t0 + tid;
        int tt = t;
        if (dir) { int L = lens[b]; if (t < L) tt = L - 1 - t; }
        tok_s[tid] = sent[b * 256 + tt];
    }
    __syncthreads();

    float acc[8][8];
    #pragma unroll
    for (int i = 0; i < 8; ++i)
        #pragma unroll
        for (int j = 0; j < 8; ++j) acc[i][j] = 0.f;

    const int lrow = tid >> 3;
    const int l8 = tid & 7;
    const int tx = tid & 15, ty = tid >> 4;

    for (int kc = 0; kc < 256; kc += 32) {
        #pragma unroll
        for (int it = 0; it < 4; ++it) {
            int row = lrow + it * 32;
            float4 va = *(const float4*)(emb + (size_t)tok_s[row] * 256 + kc + l8 * 4);
            At[l8*4+0][row] = va.x; At[l8*4+1][row] = va.y;
            At[l8*4+2][row] = va.z; At[l8*4+3][row] = va.w;
            float4 vb = *(const float4*)(wih + (size_t)(j0 + row) * 256 + kc + l8 * 4);
            Bt[l8*4+0][row] = vb.x; Bt[l8*4+1][row] = vb.y;
            Bt[l8*4+2][row] = vb.z; Bt[l8*4+3][row] = vb.w;
        }
        __syncthreads();
        #pragma unroll
        for (int k = 0; k < 32; ++k) {
            float4 a0 = *(const float4*)&At[k][ty*8];
            float4 a1 = *(const float4*)&At[k][ty*8+4];
            float4 b0 = *(const float4*)&Bt[k][tx*8];
            float4 b1 = *(const float4*)&Bt[k][tx*8+4];
            float av[8] = {a0.x,a0.y,a0.z,a0.w,a1.x,a1.y,a1.z,a1.w};
            float bv[8] = {b0.x,b0.y,b0.z,b0.w,b1.x,b1.y,b1.z,b1.w};
            #pragma unroll
            for (int i = 0; i < 8; ++i)
                #pragma unroll
                for (int j = 0; j < 8; ++j)
                    acc[i][j] += av[i] * bv[j];
        }
        __syncthreads();
    }

    float bias[8];
    {
        float4 p0 = *(const float4*)(bih + j0 + tx*8);
        float4 p1 = *(const float4*)(bih + j0 + tx*8 + 4);
        float4 q0 = *(const float4*)(bhh + j0 + tx*8);
        float4 q1 = *(const float4*)(bhh + j0 + tx*8 + 4);
        bias[0]=p0.x+q0.x; bias[1]=p0.y+q0.y; bias[2]=p0.z+q0.z; bias[3]=p0.w+q0.w;
        bias[4]=p1.x+q1.x; bias[5]=p1.y+q1.y; bias[6]=p1.z+q1.z; bias[7]=p1.w+q1.w;
    }
    #pragma unroll
    for (int i = 0; i < 8; ++i) {
        int r = r0 + ty*8 + i;
        int t = r & 255;
        float* orow = xg + ((size_t)(dir*64 + b) * 256 + t) * 1024 + j0 + tx*8;
        float4 o0, o1;
        o0.x = acc[i][0]+bias[0]; o0.y = acc[i][1]+bias[1];
        o0.z = acc[i][2]+bias[2]; o0.w = acc[i][3]+bias[3];
        o1.x = acc[i][4]+bias[4]; o1.y = acc[i][5]+bias[5];
        o1.z = acc[i][6]+bias[6]; o1.w = acc[i][7]+bias[7];
        *(float4*)orow = o0;
        *(float4*)(orow + 4) = o1;
    }
}

// ---------------------------------------------------------------- K2: weight-stationary LSTM
// 256 WGs x 512 thr: member m = blockIdx>>6 (64-unit slice), group g = blockIdx&63.
// Thread (kg=tid>>6, q=tid&63): 4 rows {gate=q>>4, units (q&15)*4..+3} x k[kg*32,+32)
// = 128 weights in VGPRs. Step: A(LDS hs read, 256 FMA, red write) -> b1 ->
// {BC: reduce+cell+hx(sc1)+flag(release) || loader: backoff poll + 1 ull sc1
// load + hs/hcat write} -> b2.
__global__ __launch_bounds__(512)
__attribute__((amdgpu_waves_per_eu(2, 2)))
void k2_lstm(
    const float* __restrict__ whh_f, const float* __restrict__ whh_b,
    const float* __restrict__ xg, float* __restrict__ hcat,
    float* __restrict__ hx, unsigned int* __restrict__ flags)
{
    const int m = blockIdx.x >> 6;       // slice / member 0..3
    const int g = blockIdx.x & 63;       // group
    const int dir = g >> 5;
    const int b0 = (g & 31) * 2;
    const float* __restrict__ w = dir ? whh_b : whh_f;

    const int tid = threadIdx.x;
    const int kg = tid >> 6;             // 0..7 (wave-uniform)
    const int q  = tid & 63;
    const int gate = q >> 4;             // 0..3
    const int u0 = (q & 15) * 4;         // unit quad base
    const int kbase = kg * 32;
    const int j0 = gate * 256 + m * 64 + u0;   // global row base (4 rows)

    // ---- 128 weights -> VGPRs, pinned with asm value barriers
    float4 wv[4][8];
    #pragma unroll
    for (int j = 0; j < 4; ++j) {
        const float* wp = w + (size_t)(j0 + j) * 256 + kbase;
        #pragma unroll
        for (int i = 0; i < 8; ++i)
            wv[j][i] = *(const float4*)(wp + i * 4);
    }
    #pragma unroll
    for (int j = 0; j < 4; ++j)
        #pragma unroll
        for (int i = 0; i < 8; ++i)
            asm volatile("" : "+v"(wv[j][i].x), "+v"(wv[j][i].y),
                              "+v"(wv[j][i].z), "+v"(wv[j][i].w));

    __shared__ __align__(16) float hs[2][256];        // h_{t-1}, both seqs
    __shared__ __align__(16) float red[8][2][256];    // 16 KB partials
    __shared__ float ldspad[20480];                   // 80 KB: forces 1 WG/CU
    if (blockIdx.x == 99999u) ldspad[tid] = 1.f;      // never true (grid=256)

    // BC mapping (tid<128): wave0 = seq0, wave1 = seq1
    const int s_c = tid >> 6, ul = tid & 63;
    const float* xgp = xg + (size_t)(dir * 64 + b0 + s_c) * 262144
                          + m * 64 + ul;              // + t*1024 + gate*256
    float* hx_w = hx + (size_t)g * 512 + s_c * 256 + m * 64 + ul;   // + par*32768
    unsigned int* flag_w = flags + ((size_t)g * 4 + m) * 16 + s_c;

    // loader mapping (tid in [256,512)): 256 threads, 2 floats each
    const int tid2 = tid - 256;                       // 0..255 (valid when tid>=256)
    const int s_r = (tid2 >> 7) & 1, pr = tid2 & 127;
    const int src = pr >> 5;                          // member owning units [2pr,2pr+1]
    const unsigned int* flag_r = flags + ((size_t)g * 4 + src) * 16 + s_r;
    const ull* hx_r = (const ull*)(hx + (size_t)g * 512 + s_r * 256) + pr; // + par*16384
    float* hc_r = hcat + (size_t)(b0 + s_r) * 131072 + dir * 256 + 2 * pr; // + t*512

    ((float*)hs)[tid & 511] = 0.f;       // zero 512 entries
    float c_reg = 0.f;
    __syncthreads();

    for (int t = 0; t < 256; ++t) {
        const int par = t & 1;

        // xg prefetch for BC (issued pre-A, latency hidden under A)
        float xp0 = 0.f, xp1 = 0.f, xp2 = 0.f, xp3 = 0.f;
        if (tid < 128) {
            const float* xq = xgp + (size_t)t * 1024;
            xp0 = xq[0]; xp1 = xq[256]; xp2 = xq[512]; xp3 = xq[768];
        }

        // ---- phase A: 4 rows x 2 seqs x 32 k from register weights
        float a0s0 = 0.f, a1s0 = 0.f, a2s0 = 0.f, a3s0 = 0.f;
        float a0s1 = 0.f, a1s1 = 0.f, a2s1 = 0.f, a3s1 = 0.f;
        #pragma unroll
        for (int i = 0; i < 8; ++i) {
            float4 ha = *(const float4*)&hs[0][kbase + i * 4];   // broadcast
            float4 hb = *(const float4*)&hs[1][kbase + i * 4];
            float4 w0 = wv[0][i], w1 = wv[1][i], w2 = wv[2][i], w3 = wv[3][i];
            a0s0 += w0.x*ha.x + w0.y*ha.y + w0.z*ha.z + w0.w*ha.w;
            a1s0 += w1.x*ha.x + w1.y*ha.y + w1.z*ha.z + w1.w*ha.w;
            a2s0 += w2.x*ha.x + w2.y*ha.y + w2.z*ha.z + w2.w*ha.w;
            a3s0 += w3.x*ha.x + w3.y*ha.y + w3.z*ha.z + w3.w*ha.w;
            a0s1 += w0.x*hb.x + w0.y*hb.y + w0.z*hb.z + w0.w*hb.w;
            a1s1 += w1.x*hb.x + w1.y*hb.y + w1.z*hb.z + w1.w*hb.w;
            a2s1 += w2.x*hb.x + w2.y*hb.y + w2.z*hb.z + w2.w*hb.w;
            a3s1 += w3.x*hb.x + w3.y*hb.y + w3.z*hb.z + w3.w*hb.w;
        }
        float4 r0v; r0v.x = a0s0; r0v.y = a1s0; r0v.z = a2s0; r0v.w = a3s0;
        float4 r1v; r1v.x = a0s1; r1v.y = a1s1; r1v.z = a2s1; r1v.w = a3s1;
        *(float4*)&red[kg][0][q * 4] = r0v;     // rows gate*64 + u0..u0+3
        *(float4*)&red[kg][1][q * 4] = r1v;
        __syncthreads();                                   // b1

        // ---- phase BC (waves 0-1)  ||  loader (waves 4-7)
        if (tid < 128) {
            float gi = xp0, gf = xp1, gg = xp2, go = xp3;
            #pragma unroll
            for (int kk = 0; kk < 8; ++kk) {
                gi += red[kk][s_c][ul];            // gate 0 rows [0,64)
                gf += red[kk][s_c][64 + ul];
                gg += red[kk][s_c][128 + ul];
                go += red[kk][s_c][192 + ul];
            }
            float si = 1.f / (1.f + expf(-gi));
            float sf = 1.f / (1.f + expf(-gf));
            float so = 1.f / (1.f + expf(-go));
            c_reg = sf * c_reg + si * tanhf(gg);
            float hn = so * tanhf(c_reg);
            __hip_atomic_store(hx_w + (size_t)par * 32768, hn,
                               __ATOMIC_RELAXED, __HIP_MEMORY_SCOPE_AGENT);
            if (ul == 0)   // release: s_waitcnt vmcnt(0) covers this wave's 64 stores
                __hip_atomic_store(flag_w, (unsigned)(t + 1),
                                   __ATOMIC_RELEASE, __HIP_MEMORY_SCOPE_AGENT);
        } else if (tid >= 256) {
            const unsigned tgt = (unsigned)(t + 1);
            // fast-path probe, then s_sleep backoff: keeps the coherence point
            // from drowning in poll traffic (R6's 12.6k-cy/step wait).
            if (__hip_atomic_load(flag_r, __ATOMIC_RELAXED,
                                  __HIP_MEMORY_SCOPE_AGENT) < tgt) {
                do {
                    __builtin_amdgcn_s_sleep(1);
                } while (__hip_atomic_load(flag_r, __ATOMIC_RELAXED,
                                           __HIP_MEMORY_SCOPE_AGENT) < tgt);
            }
            ull dv = __hip_atomic_load(hx_r + (size_t)par * 16384,
                                       __ATOMIC_RELAXED, __HIP_MEMORY_SCOPE_AGENT);
            union { ull u; float2 f; } cv; cv.u = dv;
            *(float2*)&hs[s_r][2 * pr] = cv.f;
            *(float2*)(hc_r + (size_t)t * 512) = cv.f;   // fire & forget
        }
        __syncthreads();                                   // b2
    }
}

// ---------------------------------------------------------------- K3: emissions
__global__ __launch_bounds__(256) void k3_emis(
    const float* __restrict__ hcat, const float* __restrict__ wout,
    const float* __restrict__ bout, const int* __restrict__ lens,
    float* __restrict__ em)
{
    const int b = blockIdx.x >> 3;
    const int tt0 = (blockIdx.x & 7) * 32;
    __shared__ float wsw[512 * 32];
    const int tid = threadIdx.x;
    for (int i = tid; i < 16384; i += 256) {
        int c_ = i >> 9, k_ = i & 511;
        wsw[k_ * 32 + ((k_ + c_) & 31)] = wout[i];
    }
    __syncthreads();
    const int c = tid & 31, tq = tid >> 5;
    const int L = lens[b];
    float acc[4];
    const float* hfp[4];
    const float* hbp[4];
    int tv[4];
    #pragma unroll
    for (int i = 0; i < 4; ++i) {
        int t = tt0 + i * 8 + tq;
        tv[i] = t;
        int tr = (t < L) ? (L - 1 - t) : t;
        hfp[i] = hcat + ((size_t)b * 256 + t) * 512;
        hbp[i] = hcat + ((size_t)b * 256 + tr) * 512 + 256;
        acc[i] = bout[c];
    }
    for (int k = 0; k < 256; k += 4) {
        float w0 = wsw[(k+0)*32 + ((k+0+c)&31)];
        float w1 = wsw[(k+1)*32 + ((k+1+c)&31)];
        float w2_ = wsw[(k+2)*32 + ((k+2+c)&31)];
        float w3 = wsw[(k+3)*32 + ((k+3+c)&31)];
        #pragma unroll
        for (int i = 0; i < 4; ++i) {
            float4 h = *(const float4*)(hfp[i] + k);
            acc[i] += h.x*w0 + h.y*w1 + h.z*w2_ + h.w*w3;
        }
        float v0 = wsw[(256+k+0)*32 + ((256+k+0+c)&31)];
        float v1 = wsw[(256+k+1)*32 + ((256+k+1+c)&31)];
        float v2 = wsw[(256+k+2)*32 + ((256+k+2+c)&31)];
        float v3 = wsw[(256+k+3)*32 + ((256+k+3+c)&31)];
        #pragma unroll
        for (int i = 0; i < 4; ++i) {
            float4 h = *(const float4*)(hbp[i] + k);
            acc[i] += h.x*v0 + h.y*v1 + h.z*v2 + h.w*v3;
        }
    }
    #pragma unroll
    for (int i = 0; i < 4; ++i)
        em[((size_t)b * 256 + tv[i]) * 32 + c] = acc[i];
}

// ---------------------------------------------------------------- K4: Viterbi fwd + backtrace
__global__ __launch_bounds__(256) void k4_viterbi(
    const float* __restrict__ em, const int* __restrict__ lens,
    const float* __restrict__ strans, const float* __restrict__ etrans,
    const float* __restrict__ trans, float* __restrict__ out)
{
    const int b = blockIdx.x;
    __shared__ float em_s[8192];
    __shared__ float trans_t[32 * 33];
    __shared__ float score_s[32];
    __shared__ float fin[32];
    __shared__ unsigned char hist[256][32];
    __shared__ unsigned char path[256];
    __shared__ float bs_s;
    const int tid = threadIdx.x;
    for (int i = tid; i < 8192; i += 256) em_s[i] = em[(size_t)b * 8192 + i];
    for (int i = tid; i < 1024; i += 256) {
        int p = i >> 5, cc = i & 31;
        trans_t[cc * 33 + p] = trans[i];
    }
    __syncthreads();
    if (tid < 32) score_s[tid] = strans[tid] + em_s[tid];
    __syncthreads();
    const int c = tid >> 3, pg = tid & 7;
    const int L = lens[b];
    for (int t = 1; t < 256; ++t) {
        float v = -1e30f; int bi = 0;
        #pragma unroll
        for (int i = 0; i < 4; ++i) {
            int p = pg * 4 + i;
            float cand = score_s[p] + trans_t[c * 33 + p];
            if (cand > v) { v = cand; bi = p; }
        }
        #pragma unroll
        for (int off = 4; off >= 1; off >>= 1) {
            float ov = __shfl_down(v, off);
            int oi = __shfl_down(bi, off);
            if (ov > v) { v = ov; bi = oi; }
        }
        float ns = 0.f;
        if (pg == 0) {
            hist[t][c] = (unsigned char)bi;
            ns = (t < L) ? (v + em_s[t * 32 + c]) : score_s[c];
        }
        __syncthreads();
        if (pg == 0) score_s[c] = ns;
        __syncthreads();
    }
    if (tid < 32) fin[tid] = score_s[tid] + etrans[tid];
    __syncthreads();
    if (tid == 0) {
        float bv = -1e30f; int bl = 0;
        for (int cc = 0; cc < 32; ++cc)
            if (fin[cc] > bv) { bv = fin[cc]; bl = cc; }
        bs_s = bv;
        int tag = bl;
        path[255] = (unsigned char)tag;
        for (int t = 254; t >= 0; --t) {
            if (t < L - 1) tag = hist[t + 1][tag];
            path[t] = (unsigned char)tag;
        }
    }
    __syncthreads();
    out[(size_t)b * 256 + tid] = (float)path[tid];
    if (tid == 0) out[16384 + b] = bs_s;
}

// ---------------------------------------------------------------- launch
extern "C" void kernel_launch(void* const* d_in, const int* in_sizes, int n_in,
                              void* d_out, int out_size, void* d_ws, size_t ws_size,
                              hipStream_t stream)
{
    const int*   sent   = (const int*)  d_in[0];
    const int*   lens   = (const int*)  d_in[1];
    const float* emb    = (const float*)d_in[2];
    const float* wih_f  = (const float*)d_in[3];
    const float* whh_f  = (const float*)d_in[4];
    const float* bih_f  = (const float*)d_in[5];
    const float* bhh_f  = (const float*)d_in[6];
    const float* wih_b  = (const float*)d_in[7];
    const float* whh_b  = (const float*)d_in[8];
    const float* bih_b  = (const float*)d_in[9];
    const float* bhh_b  = (const float*)d_in[10];
    const float* wout   = (const float*)d_in[11];
    const float* bout   = (const float*)d_in[12];
    const float* strans = (const float*)d_in[13];
    const float* etrans = (const float*)d_in[14];
    const float* trans  = (const float*)d_in[15];
    float* out = (float*)d_out;

    float* ws   = (float*)d_ws;
    float* xg   = ws;                        // 33554432
    float* hcat = xg + 33554432;             // 8388608
    float* em   = hcat + 8388608;            // 524288
    float* hx   = em + 524288;               // 65536
    unsigned int* flags = (unsigned int*)(hx + 65536);  // 4096

    hipLaunchKernelGGL(k0z_zero, dim3(4), dim3(1024), 0, stream, flags);
    hipLaunchKernelGGL(k1_xgemm, dim3(2048), dim3(256), 0, stream,
                       sent, lens, emb, wih_f, wih_b, bih_f, bhh_f, bih_b, bhh_b, xg);
    hipLaunchKernelGGL(k2_lstm, dim3(256), dim3(512), 0, stream,
                       whh_f, whh_b, xg, hcat, hx, flags);
    hipLaunchKernelGGL(k3_emis, dim3(512), dim3(256), 0, stream,
                       hcat, wout, bout, lens, em);
    hipLaunchKernelGGL(k4_viterbi, dim3(64), dim3(256), 0, stream,
                       em, lens, strans, etrans, trans, out);
}

// Round 9
// 1016.696 us; speedup vs baseline: 34.1487x; 1.8931x over previous
//
#include <hip/hip_runtime.h>
#include <math.h>

// BiLSTM-CRF, fp32. V=50000 B=64 T=256 D=256 H=256 C=32
//
// R8: weight-stationary LSTM; exchange via TAG-EMBEDDED 64-bit words
// ((t+1)<<32 | h_bits) with relaxed sc1 stores/loads — the data IS the flag
// (no release, no vmcnt drain, no separate flag hop). Barriers are raw
// "s_waitcnt lgkmcnt(0); s_barrier" (skip vmem drain; hx/hcat stores are
// fire-and-forget, retired by kernel end). Poisoned 0xAA tags never match
// any t+1 (exact-match poll) -> no zero-init kernel needed.
//
// ws layout (floats):
//   xg    : [2][64][256][1024]          33554432
//   hcat  : [64][256][512]               8388608
//   em    : [64][256][32]                 524288
//   hx    : [2par][64grp][2seq][256] ull  131072 floats (512 KB)
//
// d_out: float32[16448] = paths[64][256] (as float) then best_score[64]

typedef unsigned long long ull;

__device__ __forceinline__ void bar_lds()
{
    asm volatile("s_waitcnt lgkmcnt(0)\n\ts_barrier" ::: "memory");
}

// ---------------------------------------------------------------- K1: embed + input GEMM
__global__ __launch_bounds__(256) void k1_xgemm(
    const int* __restrict__ sent, const int* __restrict__ lens,
    const float* __restrict__ emb,
    const float* __restrict__ wih_f, const float* __restrict__ wih_b,
    const float* __restrict__ bih_f, const float* __restrict__ bhh_f,
    const float* __restrict__ bih_b, const float* __restrict__ bhh_b,
    float* __restrict__ xg)
{
    const int bid = blockIdx.x;          // 2048 = 2 dir * 128 mt * 8 nt
    const int dir = bid >> 10;
    const int rem = bid & 1023;
    const int mt = rem >> 3, nt = rem & 7;
    const int r0 = mt * 128, j0 = nt * 128;
    const int b = r0 >> 8, t0 = r0 & 255;
    const float* __restrict__ wih = dir ? wih_b : wih_f;
    const float* __restrict__ bih = dir ? bih_b : bih_f;
    const float* __restrict__ bhh = dir ? bhh_b : bhh_f;

    __shared__ __align__(16) float At[32][132];
    __shared__ __align__(16) float Bt[32][132];
    __shared__ int tok_s[128];

    const int tid = threadIdx.x;
    if (tid < 128) {
        int t = t0 + tid;
        int tt = t;
        if (dir) { int L = lens[b]; if (t < L) tt = L - 1 - t; }
        tok_s[tid] = sent[b * 256 + tt];
    }
    __syncthreads();

    float acc[8][8];
    #pragma unroll
    for (int i = 0; i < 8; ++i)
        #pragma unroll
        for (int j = 0; j < 8; ++j) acc[i][j] = 0.f;

    const int lrow = tid >> 3;
    const int l8 = tid & 7;
    const int tx = tid & 15, ty = tid >> 4;

    for (int kc = 0; kc < 256; kc += 32) {
        #pragma unroll
        for (int it = 0; it < 4; ++it) {
            int row = lrow + it * 32;
            float4 va = *(const float4*)(emb + (size_t)tok_s[row] * 256 + kc + l8 * 4);
            At[l8*4+0][row] = va.x; At[l8*4+1][row] = va.y;
            At[l8*4+2][row] = va.z; At[l8*4+3][row] = va.w;
            float4 vb = *(const float4*)(wih + (size_t)(j0 + row) * 256 + kc + l8 * 4);
            Bt[l8*4+0][row] = vb.x; Bt[l8*4+1][row] = vb.y;
            Bt[l8*4+2][row] = vb.z; Bt[l8*4+3][row] = vb.w;
        }
        __syncthreads();
        #pragma unroll
        for (int k = 0; k < 32; ++k) {
            float4 a0 = *(const float4*)&At[k][ty*8];
            float4 a1 = *(const float4*)&At[k][ty*8+4];
            float4 b0 = *(const float4*)&Bt[k][tx*8];
            float4 b1 = *(const float4*)&Bt[k][tx*8+4];
            float av[8] = {a0.x,a0.y,a0.z,a0.w,a1.x,a1.y,a1.z,a1.w};
            float bv[8] = {b0.x,b0.y,b0.z,b0.w,b1.x,b1.y,b1.z,b1.w};
            #pragma unroll
            for (int i = 0; i < 8; ++i)
                #pragma unroll
                for (int j = 0; j < 8; ++j)
                    acc[i][j] += av[i] * bv[j];
        }
        __syncthreads();
    }

    float bias[8];
    {
        float4 p0 = *(const float4*)(bih + j0 + tx*8);
        float4 p1 = *(const float4*)(bih + j0 + tx*8 + 4);
        float4 q0 = *(const float4*)(bhh + j0 + tx*8);
        float4 q1 = *(const float4*)(bhh + j0 + tx*8 + 4);
        bias[0]=p0.x+q0.x; bias[1]=p0.y+q0.y; bias[2]=p0.z+q0.z; bias[3]=p0.w+q0.w;
        bias[4]=p1.x+q1.x; bias[5]=p1.y+q1.y; bias[6]=p1.z+q1.z; bias[7]=p1.w+q1.w;
    }
    #pragma unroll
    for (int i = 0; i < 8; ++i) {
        int r = r0 + ty*8 + i;
        int t = r & 255;
        float* orow = xg + ((size_t)(dir*64 + b) * 256 + t) * 1024 + j0 + tx*8;
        float4 o0, o1;
        o0.x = acc[i][0]+bias[0]; o0.y = acc[i][1]+bias[1];
        o0.z = acc[i][2]+bias[2]; o0.w = acc[i][3]+bias[3];
        o1.x = acc[i][4]+bias[4]; o1.y = acc[i][5]+bias[5];
        o1.z = acc[i][6]+bias[6]; o1.w = acc[i][7]+bias[7];
        *(float4*)orow = o0;
        *(float4*)(orow + 4) = o1;
    }
}

// ---------------------------------------------------------------- K2: weight-stationary LSTM
// 256 WGs x 512 thr: member m = blockIdx>>6 (64-unit slice), group g = blockIdx&63.
// Thread (kg=tid>>6, q=tid&63): 4 rows {gate=q>>4, units (q&15)*4..+3} x k[kg*32,+32)
// = 128 weights in register file. Step: A(LDS hs, 256 FMA, red write) -> b1 ->
// {BC: reduce+cell+tagged sc1 store+hcat store || loader: poll tag==t+1, LDS hs}
// -> b2. Barriers drain LDS only.
__global__ __launch_bounds__(512)
__attribute__((amdgpu_waves_per_eu(2, 2)))
void k2_lstm(
    const float* __restrict__ whh_f, const float* __restrict__ whh_b,
    const float* __restrict__ xg, float* __restrict__ hcat,
    ull* __restrict__ hx)
{
    const int m = blockIdx.x >> 6;       // slice / member 0..3
    const int g = blockIdx.x & 63;       // group
    const int dir = g >> 5;
    const int b0 = (g & 31) * 2;
    const float* __restrict__ w = dir ? whh_b : whh_f;

    const int tid = threadIdx.x;
    const int kg = tid >> 6;             // 0..7 (wave-uniform)
    const int q  = tid & 63;
    const int gate = q >> 4;             // 0..3
    const int u0 = (q & 15) * 4;         // unit quad base
    const int kbase = kg * 32;
    const int j0 = gate * 256 + m * 64 + u0;   // global row base (4 rows)

    // ---- 128 weights -> register file, pinned with asm value barriers
    float4 wv[4][8];
    #pragma unroll
    for (int j = 0; j < 4; ++j) {
        const float* wp = w + (size_t)(j0 + j) * 256 + kbase;
        #pragma unroll
        for (int i = 0; i < 8; ++i)
            wv[j][i] = *(const float4*)(wp + i * 4);
    }
    #pragma unroll
    for (int j = 0; j < 4; ++j)
        #pragma unroll
        for (int i = 0; i < 8; ++i)
            asm volatile("" : "+v"(wv[j][i].x), "+v"(wv[j][i].y),
                              "+v"(wv[j][i].z), "+v"(wv[j][i].w));

    __shared__ __align__(16) float hs[2][256];        // h_{t-1}, both seqs
    __shared__ __align__(16) float red[8][2][256];    // 16 KB partials

    // BC mapping (tid<128): wave0 = seq0, wave1 = seq1
    const int s_c = tid >> 6, ul = tid & 63;
    const float* xgp = xg + (size_t)(dir * 64 + b0 + s_c) * 262144 + m * 64 + ul;
    ull* hx_w = hx + ((size_t)g * 2 + s_c) * 256 + m * 64 + ul;     // + par*32768
    float* hc_w = hcat + (size_t)(b0 + s_c) * 131072 + dir * 256 + m * 64 + ul;

    // loader mapping (tid in [256,512)): 256 threads, 2 units each
    const int tid2 = tid - 256;
    const int s_r = tid2 >> 7, pr = tid2 & 127;
    const ull* hx_r = hx + ((size_t)g * 2 + s_r) * 256 + 2 * pr;    // + par*32768

    ((float*)hs)[tid & 511] = 0.f;       // zero h_{-1}
    float c_reg = 0.f;
    bar_lds();

    for (int t = 0; t < 256; ++t) {
        const int par = t & 1;

        // xg prefetch for BC (issued pre-A, latency hidden under A)
        float xp0 = 0.f, xp1 = 0.f, xp2 = 0.f, xp3 = 0.f;
        if (tid < 128) {
            const float* xq = xgp + (size_t)t * 1024;
            xp0 = xq[0]; xp1 = xq[256]; xp2 = xq[512]; xp3 = xq[768];
        }

        // ---- phase A: 4 rows x 2 seqs x 32 k from register weights
        float a0s0 = 0.f, a1s0 = 0.f, a2s0 = 0.f, a3s0 = 0.f;
        float a0s1 = 0.f, a1s1 = 0.f, a2s1 = 0.f, a3s1 = 0.f;
        #pragma unroll
        for (int i = 0; i < 8; ++i) {
            float4 ha = *(const float4*)&hs[0][kbase + i * 4];   // broadcast
            float4 hb = *(const float4*)&hs[1][kbase + i * 4];
            float4 w0 = wv[0][i], w1 = wv[1][i], w2 = wv[2][i], w3 = wv[3][i];
            a0s0 += w0.x*ha.x + w0.y*ha.y + w0.z*ha.z + w0.w*ha.w;
            a1s0 += w1.x*ha.x + w1.y*ha.y + w1.z*ha.z + w1.w*ha.w;
            a2s0 += w2.x*ha.x + w2.y*ha.y + w2.z*ha.z + w2.w*ha.w;
            a3s0 += w3.x*ha.x + w3.y*ha.y + w3.z*ha.z + w3.w*ha.w;
            a0s1 += w0.x*hb.x + w0.y*hb.y + w0.z*hb.z + w0.w*hb.w;
            a1s1 += w1.x*hb.x + w1.y*hb.y + w1.z*hb.z + w1.w*hb.w;
            a2s1 += w2.x*hb.x + w2.y*hb.y + w2.z*hb.z + w2.w*hb.w;
            a3s1 += w3.x*hb.x + w3.y*hb.y + w3.z*hb.z + w3.w*hb.w;
        }
        float4 r0v; r0v.x = a0s0; r0v.y = a1s0; r0v.z = a2s0; r0v.w = a3s0;
        float4 r1v; r1v.x = a0s1; r1v.y = a1s1; r1v.z = a2s1; r1v.w = a3s1;
        *(float4*)&red[kg][0][q * 4] = r0v;     // rows gate*64 + u0..u0+3
        *(float4*)&red[kg][1][q * 4] = r1v;
        bar_lds();                                         // b1

        // ---- phase BC (waves 0-1)  ||  loader (waves 4-7)
        if (tid < 128) {
            float gi = xp0, gf = xp1, gg = xp2, go = xp3;
            #pragma unroll
            for (int kk = 0; kk < 8; ++kk) {
                gi += red[kk][s_c][ul];
                gf += red[kk][s_c][64 + ul];
                gg += red[kk][s_c][128 + ul];
                go += red[kk][s_c][192 + ul];
            }
            float si = 1.f / (1.f + expf(-gi));
            float sf = 1.f / (1.f + expf(-gf));
            float so = 1.f / (1.f + expf(-go));
            c_reg = sf * c_reg + si * tanhf(gg);
            float hn = so * tanhf(c_reg);
            ull pk = ((ull)(unsigned)(t + 1) << 32) | (ull)__float_as_uint(hn);
            __hip_atomic_store(hx_w + (size_t)par * 32768, pk,
                               __ATOMIC_RELAXED, __HIP_MEMORY_SCOPE_AGENT);
            hc_w[(size_t)t * 512] = hn;          // fire & forget (no drain: bar_lds)
        } else if (tid >= 256) {
            const unsigned tg = (unsigned)(t + 1);
            const ull* p = hx_r + (size_t)par * 32768;
            ull v0, v1;
            do {
                v0 = __hip_atomic_load(p,     __ATOMIC_RELAXED, __HIP_MEMORY_SCOPE_AGENT);
                v1 = __hip_atomic_load(p + 1, __ATOMIC_RELAXED, __HIP_MEMORY_SCOPE_AGENT);
            } while ((unsigned)(v0 >> 32) != tg || (unsigned)(v1 >> 32) != tg);
            hs[s_r][2 * pr]     = __uint_as_float((unsigned)v0);
            hs[s_r][2 * pr + 1] = __uint_as_float((unsigned)v1);
        }
        bar_lds();                                         // b2
    }
}

// ---------------------------------------------------------------- K3: emissions
__global__ __launch_bounds__(256) void k3_emis(
    const float* __restrict__ hcat, const float* __restrict__ wout,
    const float* __restrict__ bout, const int* __restrict__ lens,
    float* __restrict__ em)
{
    const int b = blockIdx.x >> 3;
    const int tt0 = (blockIdx.x & 7) * 32;
    __shared__ float wsw[512 * 32];
    const int tid = threadIdx.x;
    for (int i = tid; i < 16384; i += 256) {
        int c_ = i >> 9, k_ = i & 511;
        wsw[k_ * 32 + ((k_ + c_) & 31)] = wout[i];
    }
    __syncthreads();
    const int c = tid & 31, tq = tid >> 5;
    const int L = lens[b];
    float acc[4];
    const float* hfp[4];
    const float* hbp[4];
    int tv[4];
    #pragma unroll
    for (int i = 0; i < 4; ++i) {
        int t = tt0 + i * 8 + tq;
        tv[i] = t;
        int tr = (t < L) ? (L - 1 - t) : t;
        hfp[i] = hcat + ((size_t)b * 256 + t) * 512;
        hbp[i] = hcat + ((size_t)b * 256 + tr) * 512 + 256;
        acc[i] = bout[c];
    }
    for (int k = 0; k < 256; k += 4) {
        float w0 = wsw[(k+0)*32 + ((k+0+c)&31)];
        float w1 = wsw[(k+1)*32 + ((k+1+c)&31)];
        float w2_ = wsw[(k+2)*32 + ((k+2+c)&31)];
        float w3 = wsw[(k+3)*32 + ((k+3+c)&31)];
        #pragma unroll
        for (int i = 0; i < 4; ++i) {
            float4 h = *(const float4*)(hfp[i] + k);
            acc[i] += h.x*w0 + h.y*w1 + h.z*w2_ + h.w*w3;
        }
        float v0 = wsw[(256+k+0)*32 + ((256+k+0+c)&31)];
        float v1 = wsw[(256+k+1)*32 + ((256+k+1+c)&31)];
        float v2 = wsw[(256+k+2)*32 + ((256+k+2+c)&31)];
        float v3 = wsw[(256+k+3)*32 + ((256+k+3+c)&31)];
        #pragma unroll
        for (int i = 0; i < 4; ++i) {
            float4 h = *(const float4*)(hbp[i] + k);
            acc[i] += h.x*v0 + h.y*v1 + h.z*v2 + h.w*v3;
        }
    }
    #pragma unroll
    for (int i = 0; i < 4; ++i)
        em[((size_t)b * 256 + tv[i]) * 32 + c] = acc[i];
}

// ---------------------------------------------------------------- K4: Viterbi fwd + backtrace
__global__ __launch_bounds__(256) void k4_viterbi(
    const float* __restrict__ em, const int* __restrict__ lens,
    const float* __restrict__ strans, const float* __restrict__ etrans,
    const float* __restrict__ trans, float* __restrict__ out)
{
    const int b = blockIdx.x;
    __shared__ float em_s[8192];
    __shared__ float trans_t[32 * 33];
    __shared__ float score_s[32];
    __shared__ float fin[32];
    __shared__ unsigned char hist[256][32];
    __shared__ unsigned char path[256];
    __shared__ float bs_s;
    const int tid = threadIdx.x;
    for (int i = tid; i < 8192; i += 256) em_s[i] = em[(size_t)b * 8192 + i];
    for (int i = tid; i < 1024; i += 256) {
        int p = i >> 5, cc = i & 31;
        trans_t[cc * 33 + p] = trans[i];
    }
    __syncthreads();
    if (tid < 32) score_s[tid] = strans[tid] + em_s[tid];
    __syncthreads();
    const int c = tid >> 3, pg = tid & 7;
    const int L = lens[b];
    for (int t = 1; t < 256; ++t) {
        float v = -1e30f; int bi = 0;
        #pragma unroll
        for (int i = 0; i < 4; ++i) {
            int p = pg * 4 + i;
            float cand = score_s[p] + trans_t[c * 33 + p];
            if (cand > v) { v = cand; bi = p; }
        }
        #pragma unroll
        for (int off = 4; off >= 1; off >>= 1) {
            float ov = __shfl_down(v, off);
            int oi = __shfl_down(bi, off);
            if (ov > v) { v = ov; bi = oi; }
        }
        float ns = 0.f;
        if (pg == 0) {
            hist[t][c] = (unsigned char)bi;
            ns = (t < L) ? (v + em_s[t * 32 + c]) : score_s[c];
        }
        __syncthreads();
        if (pg == 0) score_s[c] = ns;
        __syncthreads();
    }
    if (tid < 32) fin[tid] = score_s[tid] + etrans[tid];
    __syncthreads();
    if (tid == 0) {
        float bv = -1e30f; int bl = 0;
        for (int cc = 0; cc < 32; ++cc)
            if (fin[cc] > bv) { bv = fin[cc]; bl = cc; }
        bs_s = bv;
        int tag = bl;
        path[255] = (unsigned char)tag;
        for (int t = 254; t >= 0; --t) {
            if (t < L - 1) tag = hist[t + 1][tag];
            path[t] = (unsigned char)tag;
        }
    }
    __syncthreads();
    out[(size_t)b * 256 + tid] = (float)path[tid];
    if (tid == 0) out[16384 + b] = bs_s;
}

// ---------------------------------------------------------------- launch
extern "C" void kernel_launch(void* const* d_in, const int* in_sizes, int n_in,
                              void* d_out, int out_size, void* d_ws, size_t ws_size,
                              hipStream_t stream)
{
    const int*   sent   = (const int*)  d_in[0];
    const int*   lens   = (const int*)  d_in[1];
    const float* emb    = (const float*)d_in[2];
    const float* wih_f  = (const float*)d_in[3];
    const float* whh_f  = (const float*)d_in[4];
    const float* bih_f  = (const float*)d_in[5];
    const float* bhh_f  = (const float*)d_in[6];
    const float* wih_b  = (const float*)d_in[7];
    const float* whh_b  = (const float*)d_in[8];
    const float* bih_b  = (const float*)d_in[9];
    const float* bhh_b  = (const float*)d_in[10];
    const float* wout   = (const float*)d_in[11];
    const float* bout   = (const float*)d_in[12];
    const float* strans = (const float*)d_in[13];
    const float* etrans = (const float*)d_in[14];
    const float* trans  = (const float*)d_in[15];
    float* out = (float*)d_out;

    float* ws   = (float*)d_ws;
    float* xg   = ws;                        // 33554432 floats
    float* hcat = xg + 33554432;             // 8388608
    float* em   = hcat + 8388608;            // 524288
    ull*   hx   = (ull*)(em + 524288);       // 65536 ull (512 KB), 8B-aligned

    hipLaunchKernelGGL(k1_xgemm, dim3(2048), dim3(256), 0, stream,
                       sent, lens, emb, wih_f, wih_b, bih_f, bhh_f, bih_b, bhh_b, xg);
    hipLaunchKernelGGL(k2_lstm, dim3(256), dim3(512), 0, stream,
                       whh_f, whh_b, xg, hcat, hx);
    hipLaunchKernelGGL(k3_emis, dim3(512), dim3(256), 0, stream,
                       hcat, wout, bout, lens, em);
    hipLaunchKernelGGL(k4_viterbi, dim3(64), dim3(256), 0, stream,
                       em, lens, strans, etrans, trans, out);
}